// Round 14
// baseline (420.779 us; speedup 1.0000x reference)
//
#include <hip/hip_runtime.h>
#include <hip/hip_bf16.h>
#include <math.h>

#define B_ 128
#define T_ 128
#define E_ 1024
#define IN_ 1074
#define H_ 256
#define G3_ 768
#define D_ 512
#define CO_ 256

typedef unsigned int uint_t;
typedef _Float16 v2h __attribute__((ext_vector_type(2)));
typedef _Float16 f16x8 __attribute__((ext_vector_type(8)));
typedef float f32x4 __attribute__((ext_vector_type(4)));

// ---------------- prep kernels ----------------

// me[dir][m][g] = bih[g] + sum_c mask_emb[m][c] * Wih[g][1024+c]
__global__ void k_prep_me(const float* __restrict__ mask_emb,
                          const float* __restrict__ Wf, const float* __restrict__ bf,
                          const float* __restrict__ Wb, const float* __restrict__ bb,
                          float* __restrict__ me) {
    int idx = blockIdx.x * 256 + threadIdx.x;   // 0..3071
    if (idx >= 2 * 2 * G3_) return;
    int dir = idx / (2 * G3_);
    int rem = idx % (2 * G3_);
    int m = rem / G3_;
    int g = rem % G3_;
    const float* W = dir ? Wb : Wf;
    const float* bi = dir ? bb : bf;
    float acc = bi[g];
    const float* wrow = W + (size_t)g * IN_ + E_;
    const float* e = mask_emb + m * 50;
    #pragma unroll 10
    for (int c = 0; c < 50; ++c) acc += e[c] * wrow[c];
    me[idx] = acc;
}

__device__ __forceinline__ uint_t pk2(float a, float b) {
    uint_t u0 = (uint_t)__builtin_bit_cast(unsigned short, (_Float16)a);
    uint_t u1 = (uint_t)__builtin_bit_cast(unsigned short, (_Float16)b);
    return u0 | (u1 << 16);
}

// per-gate-row scales for i8 Whh
__global__ void k_scale(const float* __restrict__ Wf, const float* __restrict__ Wb,
                        float* __restrict__ dq, float* __restrict__ inv) {
    int r = blockIdx.x * 256 + threadIdx.x;   // 0..1535
    if (r >= 1536) return;
    int d = r / G3_;
    int g = r % G3_;
    const float* W = (d ? Wb : Wf) + (size_t)g * H_;
    float m = 0.f;
    for (int k = 0; k < H_; ++k) m = fmaxf(m, fabsf(W[k]));
    dq[r] = m / 16129.f;
    inv[r] = (m > 0.f) ? 127.f / m : 0.f;
}

// i8 weight pack (layout unchanged from round 12)
__global__ void k_quant(const float* __restrict__ Wf, const float* __restrict__ Wb,
                        const float* __restrict__ inv, uint_t* __restrict__ wi8) {
    int i = blockIdx.x * 256 + threadIdx.x;   // 0..98303
    if (i >= 98304) return;
    int w = i & 3;
    int j = (i >> 2) & 255;
    int rest = i >> 10;
    int p = rest % 3;
    int rest2 = rest / 3;
    int q16 = rest2 & 7;
    int khd = rest2 >> 3;
    int kh = khd & 1;
    int d = khd >> 1;
    int g = p * 256 + j;
    int k0 = kh * 128 + q16 * 16 + w * 4;
    const float* W = (d ? Wb : Wf) + (size_t)g * H_ + k0;
    float iv = inv[d * G3_ + g];
    uint_t u = 0;
    #pragma unroll
    for (int c = 0; c < 4; ++c) {
        int q = __float2int_rn(W[c] * iv);
        q = max(-127, min(127, q));
        u |= ((uint_t)(q & 0xff)) << (8 * c);
    }
    wi8[i] = u;
}

// W2[co][j*512+d] = f16(conv_w[co][d][j])
__global__ void k_prep_w2(const float* __restrict__ cw, unsigned short* __restrict__ W2) {
    int i = blockIdx.x * 256 + threadIdx.x;    // 0..393215
    if (i >= CO_ * 1536) return;
    int co = i / 1536;
    int k = i % 1536;
    int j = k >> 9;
    int d = k & 511;
    float v = cw[(size_t)co * (D_ * 3) + d * 3 + j];
    W2[i] = __builtin_bit_cast(unsigned short, (_Float16)v);
}

// sents f32 -> f16 (packed)
__global__ __launch_bounds__(256) void k_cvt_sents(const float* __restrict__ in,
                                                   uint_t* __restrict__ out) {
    int i = blockIdx.x * 256 + threadIdx.x;    // 0..2097151
    float4 a = reinterpret_cast<const float4*>(in)[i * 2];
    float4 b = reinterpret_cast<const float4*>(in)[i * 2 + 1];
    uint4 o;
    o.x = pk2(a.x, a.y); o.y = pk2(a.z, a.w);
    o.z = pk2(b.x, b.y); o.w = pk2(b.z, b.w);
    reinterpret_cast<uint4*>(out)[i] = o;
}

// W16[n][k] = f16(Wih_dir[g][k])
__global__ __launch_bounds__(256) void k_cvt_w(const float* __restrict__ Wf,
                                               const float* __restrict__ Wb,
                                               uint_t* __restrict__ out) {
    int i = blockIdx.x * 256 + threadIdx.x;    // 0..196607
    if (i >= 1536 * 128) return;
    int n = i >> 7, kq = i & 127;
    int dir = n >= G3_;
    int g = n - dir * G3_;
    const float* src = (dir ? Wb : Wf) + (size_t)g * IN_ + kq * 8;
    float2 a = reinterpret_cast<const float2*>(src)[0];
    float2 b = reinterpret_cast<const float2*>(src)[1];
    float2 c = reinterpret_cast<const float2*>(src)[2];
    float2 d = reinterpret_cast<const float2*>(src)[3];
    uint4 o;
    o.x = pk2(a.x, a.y); o.y = pk2(b.x, b.y);
    o.z = pk2(c.x, c.y); o.w = pk2(d.x, d.y);
    reinterpret_cast<uint4*>(out)[i] = o;
}

// ---------------- MFMA xg GEMM (f16 output) ----------------

__device__ __forceinline__ void gload16(const void* g, void* l) {
    __builtin_amdgcn_global_load_lds(
        (const __attribute__((address_space(1))) void*)g,
        (__attribute__((address_space(3))) void*)l, 16, 0, 0);
}

__global__ __launch_bounds__(256) void k_gemm_mfma(
        const _Float16* __restrict__ A16, const _Float16* __restrict__ W16,
        const float* __restrict__ me, const int* __restrict__ masks,
        _Float16* __restrict__ xgf, _Float16* __restrict__ xgb) {
    __shared__ _Float16 As[4096];
    __shared__ _Float16 Bs[4096];
    const int bid = blockIdx.x;
    const int logical = (bid & 7) * 192 + (bid >> 3);
    const int mt = logical / 12, nt = logical % 12;
    const int bm = mt * 128, bn = nt * 128;
    const int tid = threadIdx.x;
    const int w = tid >> 6, lane = tid & 63;
    const int wr = w >> 1, wc = w & 1;

    const int rl = lane & 15;
    const int kb = (lane >> 4) * 16;
    const int st0 = w, st1 = 4 + w;
    const char* gA0 = (const char*)A16 + (size_t)(bm + st0 * 16 + rl) * 2048 + kb;
    const char* gA1 = (const char*)A16 + (size_t)(bm + st1 * 16 + rl) * 2048 + kb;
    const char* gB0 = (const char*)W16 + (size_t)(bn + st0 * 16 + rl) * 2048 + kb;
    const char* gB1 = (const char*)W16 + (size_t)(bn + st1 * 16 + rl) * 2048 + kb;
    char* lA0 = (char*)As + w * 1024;
    char* lA1 = (char*)As + 4096 + w * 1024;
    char* lB0 = (char*)Bs + w * 1024;
    char* lB1 = (char*)Bs + 4096 + w * 1024;

    f32x4 acc[4][4];
    #pragma unroll
    for (int m = 0; m < 4; ++m)
        #pragma unroll
        for (int n = 0; n < 4; ++n)
            acc[m][n] = (f32x4){0.f, 0.f, 0.f, 0.f};

    for (int kB = 0; kB < 2048; kB += 64) {
        gload16(gA0 + kB, lA0);
        gload16(gA1 + kB, lA1);
        gload16(gB0 + kB, lB0);
        gload16(gB1 + kB, lB1);
        __syncthreads();
        f16x8 af[4], bf[4];
        #pragma unroll
        for (int m = 0; m < 4; ++m)
            af[m] = *reinterpret_cast<const f16x8*>(
                (const char*)As + (wr * 4 + m) * 1024 + lane * 16);
        #pragma unroll
        for (int n = 0; n < 4; ++n)
            bf[n] = *reinterpret_cast<const f16x8*>(
                (const char*)Bs + (wc * 4 + n) * 1024 + lane * 16);
        #pragma unroll
        for (int m = 0; m < 4; ++m)
            #pragma unroll
            for (int n = 0; n < 4; ++n)
                acc[m][n] = __builtin_amdgcn_mfma_f32_16x16x32_f16(
                    af[m], bf[n], acc[m][n], 0, 0, 0);
        __syncthreads();
    }

    const int qr = (lane >> 4) * 4;
    const int cc = lane & 15;
    #pragma unroll
    for (int m = 0; m < 4; ++m) {
        #pragma unroll
        for (int q = 0; q < 4; ++q) {
            const int bt = bm + wr * 64 + m * 16 + qr + q;
            const int mk = masks[bt];
            const int b = bt >> 7, t = bt & 127;
            #pragma unroll
            for (int n = 0; n < 4; ++n) {
                const int col = bn + wc * 64 + n * 16 + cc;
                const int dir = col >= G3_;
                const int g = col - dir * G3_;
                float v = acc[m][n][q] + me[dir * (2 * G3_) + mk * G3_ + g];
                _Float16* dst = (dir ? xgb : xgf) + ((size_t)(t * B_ + b)) * G3_ + g;
                *dst = (_Float16)v;
            }
        }
    }
}

// ---------------- GRU scan (3-way weight partition: LDS / REG / stream) -------
__device__ __forceinline__ int sdot4(uint_t a, uint_t b, int c) {
#if __has_builtin(__builtin_amdgcn_sdot4)
    return __builtin_amdgcn_sdot4((int)a, (int)b, c, false);
#else
    int r = c;
    r += ((int)(a << 24) >> 24) * ((int)(b << 24) >> 24);
    r += ((int)(a << 16) >> 24) * ((int)(b << 16) >> 24);
    r += ((int)(a << 8) >> 24) * ((int)(b << 8) >> 24);
    r += ((int)a >> 24) * ((int)b >> 24);
    return r;
#endif
}

__device__ __forceinline__ int dot16(uint4 w, uint4 h, int acc) {
    acc = sdot4(w.x, h.x, acc);
    acc = sdot4(w.y, h.y, acc);
    acc = sdot4(w.z, h.z, acc);
    acc = sdot4(w.w, h.w, acc);
    return acc;
}

// One block = one (batch row, direction). 512 threads: j = tid&255, kh = tid>>8.
// 24 weight chunks (uint4)/thread. Rounds 8-13 proved the allocator spills any
// large register-resident weight set to scratch (= L2 stream at ~84 B/cyc/CU).
// So: 14 chunks live in LDS (loaded once, ds_read_b128 per step — DS pipe),
// 6 chunks in registers (small enough to survive regalloc), 4 chunks left to
// the compiler's stream (VMEM pipe). The three pipes overlap.
__global__ __launch_bounds__(512, 1) void k_gru(
        const _Float16* __restrict__ xgf, const _Float16* __restrict__ xgb,
        const uint_t* __restrict__ wi8, const float* __restrict__ dq,
        const float* __restrict__ bhhf, const float* __restrict__ bhhb,
        const int* __restrict__ lens, _Float16* __restrict__ ctx16p) {
    const int dir = blockIdx.y;
    const int b = blockIdx.x;
    const int tid = threadIdx.x;
    const int j = tid & 255;
    const int kh = tid >> 8;
    const _Float16* xg = dir ? xgb : xgf;
    const float* bhh = dir ? bhhb : bhhf;
    const uint4* wp4 = (const uint4*)wi8 + (size_t)dir * (2 * 8 * 3 * 256);
    _Float16* c16 = ctx16p + (size_t)b * (T_ + 2) * D_;

    __shared__ uint4 wl[14 * 512];       // 114,688 B of weights
    __shared__ uint_t hq_s[64];          // 256 i8 h values
    __shared__ int part[3][256];

    // zero the pad rows
    c16[tid] = (_Float16)0.f;
    c16[(size_t)(T_ + 1) * D_ + tid] = (_Float16)0.f;

    // chunk (p,q) map:  q0,q1 -> REG;  q2..q5 (all p) + q6 (p0,p1) -> LDS;
    //                   q6 p2, q7 (all p) -> VMEM stream
    // LDS fill (each thread stores its own 14 chunks)
    #pragma unroll
    for (int s = 0; s < 12; ++s) {
        const int q = 2 + s / 3, p = s % 3;
        wl[s * 512 + tid] = wp4[((size_t)((kh * 8 + q) * 3 + p)) * 256 + j];
    }
    #pragma unroll
    for (int p = 0; p < 2; ++p)
        wl[(12 + p) * 512 + tid] = wp4[((size_t)((kh * 8 + 6) * 3 + p)) * 256 + j];

    // REG chunks q0,q1 (6 uint4 = 24 VGPR), pinned
    uint4 wr0[3], wr1[3];
    #pragma unroll
    for (int p = 0; p < 3; ++p) {
        wr0[p] = wp4[((size_t)((kh * 8 + 0) * 3 + p)) * 256 + j];
        wr1[p] = wp4[((size_t)((kh * 8 + 1) * 3 + p)) * 256 + j];
    }
    #pragma unroll
    for (int p = 0; p < 3; ++p) {
        asm volatile("" : "+v"(wr0[p].x), "+v"(wr0[p].y), "+v"(wr0[p].z), "+v"(wr0[p].w));
        asm volatile("" : "+v"(wr1[p].x), "+v"(wr1[p].y), "+v"(wr1[p].z), "+v"(wr1[p].w));
    }

    // stream chunk addresses
    const uint4* pv62 = wp4 + ((size_t)((kh * 8 + 6) * 3 + 2)) * 256 + j;
    const uint4* pv70 = wp4 + ((size_t)((kh * 8 + 7) * 3 + 0)) * 256 + j;
    const uint4* pv71 = wp4 + ((size_t)((kh * 8 + 7) * 3 + 1)) * 256 + j;
    const uint4* pv72 = wp4 + ((size_t)((kh * 8 + 7) * 3 + 2)) * 256 + j;

    if (tid < 64) hq_s[tid] = 0u;
    const int len = lens[b];
    const float dq0 = dq[dir * G3_ + j];
    const float dq1 = dq[dir * G3_ + 256 + j];
    const float dq2 = dq[dir * G3_ + 512 + j];
    const float bh0 = bhh[j], bh1 = bhh[H_ + j], bh2 = bhh[2 * H_ + j];
    float hcur = 0.f;
    float g0 = 0.f, g1 = 0.f, g2 = 0.f;
    int t = dir ? (T_ - 1) : 0;
    if (kh == 0) {
        const _Float16* r = xg + ((size_t)(t * B_ + b)) * G3_;
        g0 = (float)r[j]; g1 = (float)r[H_ + j]; g2 = (float)r[2 * H_ + j];
    }
    __syncthreads();

    const uint4* hq4 = (const uint4*)hq_s;
    for (int s = 0; s < T_; ++s) {
        const int tn = dir ? (T_ - 2 - s) : (s + 1);
        float n0 = 0.f, n1 = 0.f, n2 = 0.f;
        if (kh == 0 && s < T_ - 1) {
            const _Float16* r = xg + ((size_t)(tn * B_ + b)) * G3_;
            n0 = (float)r[j]; n1 = (float)r[H_ + j]; n2 = (float)r[2 * H_ + j];
        }
        // stream loads issued first (VMEM pipe, overlaps DS reads below)
        uint4 t62 = *pv62;
        uint4 t70 = *pv70;
        uint4 t71 = *pv71;
        uint4 t72 = *pv72;
        // h chunks (broadcast reads)
        uint4 hv[8];
        #pragma unroll
        for (int q = 0; q < 8; ++q) hv[q] = hq4[kh * 8 + q];
        int a0 = 0, a1 = 0, a2 = 0;
        // REG dots (q0,q1)
        a0 = dot16(wr0[0], hv[0], a0); a1 = dot16(wr0[1], hv[0], a1); a2 = dot16(wr0[2], hv[0], a2);
        a0 = dot16(wr1[0], hv[1], a0); a1 = dot16(wr1[1], hv[1], a1); a2 = dot16(wr1[2], hv[1], a2);
        // LDS dots (q2..q5 all gates, q6 gates 0,1)
        #pragma unroll
        for (int ss = 0; ss < 12; ++ss) {
            const int q = 2 + ss / 3, p = ss % 3;
            uint4 wv = wl[ss * 512 + tid];
            if (p == 0) a0 = dot16(wv, hv[q], a0);
            else if (p == 1) a1 = dot16(wv, hv[q], a1);
            else a2 = dot16(wv, hv[q], a2);
        }
        a0 = dot16(wl[12 * 512 + tid], hv[6], a0);
        a1 = dot16(wl[13 * 512 + tid], hv[6], a1);
        // stream dots (q6 p2, q7 all gates)
        a2 = dot16(t62, hv[6], a2);
        a0 = dot16(t70, hv[7], a0);
        a1 = dot16(t71, hv[7], a1);
        a2 = dot16(t72, hv[7], a2);

        if (kh == 1) {
            part[0][j] = a0; part[1][j] = a1; part[2][j] = a2;
        }
        __syncthreads();
        if (kh == 0) {
            float A0 = (float)(a0 + part[0][j]) * dq0;
            float A1 = (float)(a1 + part[1][j]) * dq1;
            float A2 = (float)(a2 + part[2][j]) * dq2;
            float rg = 1.f / (1.f + expf(-(g0 + A0 + bh0)));
            float zg = 1.f / (1.f + expf(-(g1 + A1 + bh1)));
            float ng = tanhf(g2 + rg * (A2 + bh2));
            float v = (1.f - zg) * ng + zg * hcur;
            hcur = (t < len) ? v : hcur;
            c16[(size_t)(t + 1) * D_ + dir * H_ + j] = (_Float16)hcur;
            int qi = __float2int_rn(hcur * 127.f);
            ((signed char*)hq_s)[j] = (signed char)qi;
        }
        __syncthreads();
        g0 = n0; g1 = n1; g2 = n2;
        t = tn;
    }
}

// ---------------- conv1d as MFMA GEMM ----------------
__global__ __launch_bounds__(256) void k_conv_mfma(
        const _Float16* __restrict__ C16, const _Float16* __restrict__ W2,
        const float* __restrict__ cb, float* __restrict__ ctx2) {
    __shared__ _Float16 As[4096];
    __shared__ _Float16 Bs[4096];
    const int b = blockIdx.x >> 1;
    const int nt = blockIdx.x & 1;
    const int bn = nt * 128;
    const int tid = threadIdx.x;
    const int w = tid >> 6, lane = tid & 63;
    const int wr = w >> 1, wc = w & 1;
    const int rl = lane & 15;
    const int kb = (lane >> 4) * 16;
    const char* gA0 = (const char*)C16 + ((size_t)(b * (T_ + 2) + w * 16 + rl)) * 1024 + kb;
    const char* gA1 = (const char*)C16 + ((size_t)(b * (T_ + 2) + 64 + w * 16 + rl)) * 1024 + kb;
    const char* gB0 = (const char*)W2 + (size_t)(bn + w * 16 + rl) * 3072 + kb;
    const char* gB1 = (const char*)W2 + (size_t)(bn + 64 + w * 16 + rl) * 3072 + kb;
    char* lA0 = (char*)As + w * 1024;
    char* lA1 = (char*)As + 4096 + w * 1024;
    char* lB0 = (char*)Bs + w * 1024;
    char* lB1 = (char*)Bs + 4096 + w * 1024;

    f32x4 acc[4][4];
    #pragma unroll
    for (int m = 0; m < 4; ++m)
        #pragma unroll
        for (int n = 0; n < 4; ++n)
            acc[m][n] = (f32x4){0.f, 0.f, 0.f, 0.f};

    for (int kB = 0; kB < 3072; kB += 64) {
        gload16(gA0 + kB, lA0);
        gload16(gA1 + kB, lA1);
        gload16(gB0 + kB, lB0);
        gload16(gB1 + kB, lB1);
        __syncthreads();
        f16x8 af[4], bf[4];
        #pragma unroll
        for (int m = 0; m < 4; ++m)
            af[m] = *reinterpret_cast<const f16x8*>(
                (const char*)As + (wr * 4 + m) * 1024 + lane * 16);
        #pragma unroll
        for (int n = 0; n < 4; ++n)
            bf[n] = *reinterpret_cast<const f16x8*>(
                (const char*)Bs + (wc * 4 + n) * 1024 + lane * 16);
        #pragma unroll
        for (int m = 0; m < 4; ++m)
            #pragma unroll
            for (int n = 0; n < 4; ++n)
                acc[m][n] = __builtin_amdgcn_mfma_f32_16x16x32_f16(
                    af[m], bf[n], acc[m][n], 0, 0, 0);
        __syncthreads();
    }

    const int qr = (lane >> 4) * 4;
    const int cc = lane & 15;
    #pragma unroll
    for (int m = 0; m < 4; ++m) {
        #pragma unroll
        for (int q = 0; q < 4; ++q) {
            const int t = wr * 64 + m * 16 + qr + q;
            #pragma unroll
            for (int n = 0; n < 4; ++n) {
                const int co = bn + wc * 64 + n * 16 + cc;
                float v = acc[m][n][q] + cb[co];
                ctx2[((size_t)(b * T_ + t)) * CO_ + co] = fmaxf(v, 0.f);
            }
        }
    }
}

// ---------------- feats + CRF + pooled head (wave-parallel) ----------------
__global__ __launch_bounds__(256) void k_head(
        const float* __restrict__ ctx2, const float* __restrict__ W_tri,
        const float* __restrict__ b_tri, const float* __restrict__ trans,
        const float* __restrict__ W_lab, const float* __restrict__ b_lab,
        const int* __restrict__ lens, const int* __restrict__ labels,
        float* __restrict__ loss_b, float* __restrict__ spsum_b) {
    const int b = blockIdx.x;
    const int tid = threadIdx.x;
    const int w = tid >> 6, lane = tid & 63;
    __shared__ float f_s[T_][4];
    __shared__ float al[T_][4];
    __shared__ float be[T_][4];
    __shared__ float sp_s[T_];
    __shared__ float sv_s[CO_];
    __shared__ float sred[4];
    __shared__ float s_spsum;
    const int len = lens[b];
    const float* base = ctx2 + (size_t)b * T_ * CO_;

    {
        float wt[4][4];
        #pragma unroll
        for (int k = 0; k < 4; ++k)
            #pragma unroll
            for (int q = 0; q < 4; ++q)
                wt[k][q] = W_tri[k * CO_ + lane + 64 * q];
        float bt0 = b_tri[0], bt1 = b_tri[1], bt2 = b_tri[2], bt3 = b_tri[3];
        for (int t = w; t < T_; t += 4) {
            const float* row = base + (size_t)t * CO_;
            float v0 = row[lane], v1 = row[lane + 64],
                  v2 = row[lane + 128], v3 = row[lane + 192];
            float p0 = v0 * wt[0][0] + v1 * wt[0][1] + v2 * wt[0][2] + v3 * wt[0][3];
            float p1 = v0 * wt[1][0] + v1 * wt[1][1] + v2 * wt[1][2] + v3 * wt[1][3];
            float p2 = v0 * wt[2][0] + v1 * wt[2][1] + v2 * wt[2][2] + v3 * wt[2][3];
            float p3 = v0 * wt[3][0] + v1 * wt[3][1] + v2 * wt[3][2] + v3 * wt[3][3];
            #pragma unroll
            for (int off = 32; off > 0; off >>= 1) {
                p0 += __shfl_xor(p0, off);
                p1 += __shfl_xor(p1, off);
                p2 += __shfl_xor(p2, off);
                p3 += __shfl_xor(p3, off);
            }
            if (lane == 0) {
                f_s[t][0] = p0 + bt0; f_s[t][1] = p1 + bt1;
                f_s[t][2] = p2 + bt2; f_s[t][3] = p3 + bt3;
            }
        }
    }
    __syncthreads();

    if (w == 0 && lane < 4) {
        const int j = lane;
        float tc0 = trans[0 * 4 + j], tc1 = trans[1 * 4 + j],
              tc2 = trans[2 * 4 + j], tc3 = trans[3 * 4 + j];
        float a = f_s[0][j];
        al[0][j] = a;
        for (int t = 1; t < T_; ++t) {
            float a0 = __shfl(a, 0), a1 = __shfl(a, 1),
                  a2 = __shfl(a, 2), a3 = __shfl(a, 3);
            float s0 = a0 + tc0, s1 = a1 + tc1, s2 = a2 + tc2, s3 = a3 + tc3;
            float m = fmaxf(fmaxf(s0, s1), fmaxf(s2, s3));
            float sum = expf(s0 - m) + expf(s1 - m) + expf(s2 - m) + expf(s3 - m);
            float an = f_s[t][j] + m + logf(sum);
            if (t < len) a = an;
            al[t][j] = a;
        }
    } else if (w == 1 && lane < 4) {
        const int i = lane;
        float tr0 = trans[i * 4 + 0], tr1 = trans[i * 4 + 1],
              tr2 = trans[i * 4 + 2], tr3 = trans[i * 4 + 3];
        float bb = 0.f;
        be[T_ - 1][i] = 0.f;
        for (int t = T_ - 2; t >= 0; --t) {
            float b0 = __shfl(bb, 0), b1 = __shfl(bb, 1),
                  b2 = __shfl(bb, 2), b3 = __shfl(bb, 3);
            float s0 = tr0 + f_s[t + 1][0] + b0;
            float s1 = tr1 + f_s[t + 1][1] + b1;
            float s2 = tr2 + f_s[t + 1][2] + b2;
            float s3 = tr3 + f_s[t + 1][3] + b3;
            float m = fmaxf(fmaxf(s0, s1), fmaxf(s2, s3));
            float sum = expf(s0 - m) + expf(s1 - m) + expf(s2 - m) + expf(s3 - m);
            float bn = m + logf(sum);
            if (t + 1 < len) bb = bn;
            be[t][i] = bb;
        }
    }
    __syncthreads();

    if (tid < T_) {
        int t = tid;
        float s0 = al[t][0] + be[t][0];
        float s1 = al[t][1] + be[t][1];
        float s2 = al[t][2] + be[t][2];
        float s3 = al[t][3] + be[t][3];
        float m = fmaxf(fmaxf(s0, s1), fmaxf(s2, s3));
        float e0 = expf(s0 - m), e1 = expf(s1 - m), e2 = expf(s2 - m), e3 = expf(s3 - m);
        float p1 = e1 / (e0 + e1 + e2 + e3);
        sp_s[t] = (t < len) ? p1 : 0.f;
    }
    __syncthreads();
    if (w == 0) {
        float s = sp_s[lane] + sp_s[lane + 64];
        #pragma unroll
        for (int off = 32; off > 0; off >>= 1) s += __shfl_xor(s, off);
        if (lane == 0) s_spsum = s;
    }
    __syncthreads();
    const float spsum = s_spsum;

    {
        float acc0 = 0.f, acc1 = 0.f, acc2 = 0.f, acc3 = 0.f;
        #pragma unroll 2
        for (int t = 0; t < T_; t += 4) {
            acc0 += sp_s[t + 0] * base[(size_t)(t + 0) * CO_ + tid];
            acc1 += sp_s[t + 1] * base[(size_t)(t + 1) * CO_ + tid];
            acc2 += sp_s[t + 2] * base[(size_t)(t + 2) * CO_ + tid];
            acc3 += sp_s[t + 3] * base[(size_t)(t + 3) * CO_ + tid];
        }
        sv_s[tid] = (acc0 + acc1 + acc2 + acc3) * 2.f / spsum;
    }
    __syncthreads();

    if (w < 3) {
        const float* wl_ = W_lab + w * CO_;
        float p = sv_s[lane] * wl_[lane] + sv_s[lane + 64] * wl_[lane + 64]
                + sv_s[lane + 128] * wl_[lane + 128] + sv_s[lane + 192] * wl_[lane + 192];
        #pragma unroll
        for (int off = 32; off > 0; off >>= 1) p += __shfl_xor(p, off);
        if (lane == 0) sred[w] = p + b_lab[w];
    }
    __syncthreads();
    if (tid == 0) {
        float m = fmaxf(sred[0], fmaxf(sred[1], sred[2]));
        float lse = m + logf(expf(sred[0] - m) + expf(sred[1] - m) + expf(sred[2] - m));
        loss_b[b] = lse - sred[labels[b]];
        spsum_b[b] = spsum;
    }
}

__global__ void k_final(const float* __restrict__ loss_b, const float* __restrict__ spsum_b,
                        const float* __restrict__ trans, float* __restrict__ out) {
    __shared__ float s1[128], s2[128];
    int tid = threadIdx.x;
    s1[tid] = loss_b[tid];
    s2[tid] = spsum_b[tid];
    __syncthreads();
    for (int off = 64; off > 0; off >>= 1) {
        if (tid < off) { s1[tid] += s1[tid + off]; s2[tid] += s2[tid + off]; }
        __syncthreads();
    }
    if (tid == 0) {
        float pena = fmaxf(trans[1 * 4 + 0] - trans[0 * 4 + 0], 0.f)
                   + fmaxf(trans[0 * 4 + 1] - trans[1 * 4 + 1], 0.f);
        out[0] = s1[0] / (float)B_;
        out[1] = 0.1f * pena + 0.1f * (s2[0] / (float)B_);
    }
}

// ---------------- launch ----------------
extern "C" void kernel_launch(void* const* d_in, const int* in_sizes, int n_in,
                              void* d_out, int out_size, void* d_ws, size_t ws_size,
                              hipStream_t stream) {
    const float* sents   = (const float*)d_in[0];
    const int*   masks   = (const int*)d_in[1];
    const int*   labels  = (const int*)d_in[2];
    const int*   lens    = (const int*)d_in[3];
    const float* mask_emb= (const float*)d_in[4];
    const float* Wih_f   = (const float*)d_in[5];
    const float* Whh_f   = (const float*)d_in[6];
    const float* bih_f   = (const float*)d_in[7];
    const float* bhh_f   = (const float*)d_in[8];
    const float* Wih_b   = (const float*)d_in[9];
    const float* Whh_b   = (const float*)d_in[10];
    const float* bih_b   = (const float*)d_in[11];
    const float* bhh_b   = (const float*)d_in[12];
    const float* conv_w  = (const float*)d_in[13];
    const float* conv_b  = (const float*)d_in[14];
    const float* W_tri   = (const float*)d_in[15];
    const float* b_tri   = (const float*)d_in[16];
    const float* trans   = (const float*)d_in[17];
    const float* W_lab   = (const float*)d_in[18];
    const float* b_lab   = (const float*)d_in[19];
    float* out = (float*)d_out;
    float* ws = (float*)d_ws;

    const size_t o_xgf  = 0;
    const size_t o_xgb  = o_xgf  + (size_t)B_ * T_ * G3_;
    const size_t o_ctx  = o_xgb  + (size_t)B_ * T_ * G3_;   // sents16, then ctx16p
    const size_t o_ctx2 = o_ctx  + (size_t)B_ * T_ * D_;    // W16, then ctx2 f32
    const size_t o_wp   = o_ctx2 + (size_t)B_ * T_ * CO_;   // wi8 + dq + inv
    const size_t o_me   = o_wp   + (size_t)2 * 32 * 3 * 256 * 4;
    const size_t o_w2   = o_me   + 2 * 2 * G3_;
    const size_t o_lossb= o_w2   + (size_t)D_ * 3 * CO_;
    const size_t o_spsum= o_lossb + B_;

    _Float16* xgf16 = (_Float16*)(ws + o_xgf);
    _Float16* xgb16 = (_Float16*)(ws + o_xgb);
    float* ctx  = ws + o_ctx;
    float* ctx2 = ws + o_ctx2;
    uint_t* wi8 = (uint_t*)(ws + o_wp);                 // 98304 uints
    float* dq   = ws + o_wp + 98304;                    // 1536
    float* invs = ws + o_wp + 98304 + 1536;             // 1536
    float* me   = ws + o_me;
    unsigned short* W2 = (unsigned short*)(ws + o_w2);
    float* lossb = ws + o_lossb;
    float* spsumb = ws + o_spsum;

    _Float16* sents16 = (_Float16*)ctx;
    _Float16* ctx16p = (_Float16*)ctx;
    _Float16* W16 = (_Float16*)ctx2;    // consumed by gemm before ctx2 written

    k_prep_me<<<12, 256, 0, stream>>>(mask_emb, Wih_f, bih_f, Wih_b, bih_b, me);
    k_scale<<<6, 256, 0, stream>>>(Whh_f, Whh_b, dq, invs);
    k_quant<<<384, 256, 0, stream>>>(Whh_f, Whh_b, invs, wi8);
    k_prep_w2<<<1536, 256, 0, stream>>>(conv_w, W2);
    k_cvt_sents<<<8192, 256, 0, stream>>>(sents, (uint_t*)sents16);
    k_cvt_w<<<768, 256, 0, stream>>>(Wih_f, Wih_b, (uint_t*)W16);
    k_gemm_mfma<<<1536, 256, 0, stream>>>(sents16, W16, me, masks, xgf16, xgb16);
    k_gru<<<dim3(B_, 2), 512, 0, stream>>>(xgf16, xgb16, wi8, dq, bhh_f, bhh_b, lens, ctx16p);
    k_conv_mfma<<<256, 256, 0, stream>>>(ctx16p, (const _Float16*)W2, conv_b, ctx2);
    k_head<<<128, 256, 0, stream>>>(ctx2, W_tri, b_tri, trans, W_lab, b_lab,
                                    lens, labels, lossb, spsumb);
    k_final<<<1, 128, 0, stream>>>(lossb, spsumb, trans, out);
}

// Round 15
// 400.394 us; speedup vs baseline: 1.0509x; 1.0509x over previous
//
#include <hip/hip_runtime.h>
#include <hip/hip_bf16.h>
#include <math.h>

#define B_ 128
#define T_ 128
#define E_ 1024
#define IN_ 1074
#define H_ 256
#define G3_ 768
#define D_ 512
#define CO_ 256

typedef unsigned int uint_t;
typedef _Float16 v2h __attribute__((ext_vector_type(2)));
typedef _Float16 f16x8 __attribute__((ext_vector_type(8)));
typedef float f32x4 __attribute__((ext_vector_type(4)));

// ---------------- prep kernels ----------------

// me[dir][m][g] = bih[g] + sum_c mask_emb[m][c] * Wih[g][1024+c]
__global__ void k_prep_me(const float* __restrict__ mask_emb,
                          const float* __restrict__ Wf, const float* __restrict__ bf,
                          const float* __restrict__ Wb, const float* __restrict__ bb,
                          float* __restrict__ me) {
    int idx = blockIdx.x * 256 + threadIdx.x;   // 0..3071
    if (idx >= 2 * 2 * G3_) return;
    int dir = idx / (2 * G3_);
    int rem = idx % (2 * G3_);
    int m = rem / G3_;
    int g = rem % G3_;
    const float* W = dir ? Wb : Wf;
    const float* bi = dir ? bb : bf;
    float acc = bi[g];
    const float* wrow = W + (size_t)g * IN_ + E_;
    const float* e = mask_emb + m * 50;
    #pragma unroll 10
    for (int c = 0; c < 50; ++c) acc += e[c] * wrow[c];
    me[idx] = acc;
}

__device__ __forceinline__ uint_t pk2(float a, float b) {
    uint_t u0 = (uint_t)__builtin_bit_cast(unsigned short, (_Float16)a);
    uint_t u1 = (uint_t)__builtin_bit_cast(unsigned short, (_Float16)b);
    return u0 | (u1 << 16);
}

// per-gate-row scales for i8 Whh
__global__ void k_scale(const float* __restrict__ Wf, const float* __restrict__ Wb,
                        float* __restrict__ dq, float* __restrict__ inv) {
    int r = blockIdx.x * 256 + threadIdx.x;   // 0..1535
    if (r >= 1536) return;
    int d = r / G3_;
    int g = r % G3_;
    const float* W = (d ? Wb : Wf) + (size_t)g * H_;
    float m = 0.f;
    for (int k = 0; k < H_; ++k) m = fmaxf(m, fabsf(W[k]));
    dq[r] = m / 16129.f;
    inv[r] = (m > 0.f) ? 127.f / m : 0.f;
}

// i8 weight pack (round-12 layout)
__global__ void k_quant(const float* __restrict__ Wf, const float* __restrict__ Wb,
                        const float* __restrict__ inv, uint_t* __restrict__ wi8) {
    int i = blockIdx.x * 256 + threadIdx.x;   // 0..98303
    if (i >= 98304) return;
    int w = i & 3;
    int j = (i >> 2) & 255;
    int rest = i >> 10;
    int p = rest % 3;
    int rest2 = rest / 3;
    int q16 = rest2 & 7;
    int khd = rest2 >> 3;
    int kh = khd & 1;
    int d = khd >> 1;
    int g = p * 256 + j;
    int k0 = kh * 128 + q16 * 16 + w * 4;
    const float* W = (d ? Wb : Wf) + (size_t)g * H_ + k0;
    float iv = inv[d * G3_ + g];
    uint_t u = 0;
    #pragma unroll
    for (int c = 0; c < 4; ++c) {
        int q = __float2int_rn(W[c] * iv);
        q = max(-127, min(127, q));
        u |= ((uint_t)(q & 0xff)) << (8 * c);
    }
    wi8[i] = u;
}

// W2[co][j*512+d] = f16(conv_w[co][d][j])
__global__ void k_prep_w2(const float* __restrict__ cw, unsigned short* __restrict__ W2) {
    int i = blockIdx.x * 256 + threadIdx.x;    // 0..393215
    if (i >= CO_ * 1536) return;
    int co = i / 1536;
    int k = i % 1536;
    int j = k >> 9;
    int d = k & 511;
    float v = cw[(size_t)co * (D_ * 3) + d * 3 + j];
    W2[i] = __builtin_bit_cast(unsigned short, (_Float16)v);
}

// sents f32 -> f16 (packed)
__global__ __launch_bounds__(256) void k_cvt_sents(const float* __restrict__ in,
                                                   uint_t* __restrict__ out) {
    int i = blockIdx.x * 256 + threadIdx.x;    // 0..2097151
    float4 a = reinterpret_cast<const float4*>(in)[i * 2];
    float4 b = reinterpret_cast<const float4*>(in)[i * 2 + 1];
    uint4 o;
    o.x = pk2(a.x, a.y); o.y = pk2(a.z, a.w);
    o.z = pk2(b.x, b.y); o.w = pk2(b.z, b.w);
    reinterpret_cast<uint4*>(out)[i] = o;
}

// W16[n][k] = f16(Wih_dir[g][k])
__global__ __launch_bounds__(256) void k_cvt_w(const float* __restrict__ Wf,
                                               const float* __restrict__ Wb,
                                               uint_t* __restrict__ out) {
    int i = blockIdx.x * 256 + threadIdx.x;    // 0..196607
    if (i >= 1536 * 128) return;
    int n = i >> 7, kq = i & 127;
    int dir = n >= G3_;
    int g = n - dir * G3_;
    const float* src = (dir ? Wb : Wf) + (size_t)g * IN_ + kq * 8;
    float2 a = reinterpret_cast<const float2*>(src)[0];
    float2 b = reinterpret_cast<const float2*>(src)[1];
    float2 c = reinterpret_cast<const float2*>(src)[2];
    float2 d = reinterpret_cast<const float2*>(src)[3];
    uint4 o;
    o.x = pk2(a.x, a.y); o.y = pk2(b.x, b.y);
    o.z = pk2(c.x, c.y); o.w = pk2(d.x, d.y);
    reinterpret_cast<uint4*>(out)[i] = o;
}

// ---------------- MFMA xg GEMM (f16 output) ----------------

__device__ __forceinline__ void gload16(const void* g, void* l) {
    __builtin_amdgcn_global_load_lds(
        (const __attribute__((address_space(1))) void*)g,
        (__attribute__((address_space(3))) void*)l, 16, 0, 0);
}

__global__ __launch_bounds__(256) void k_gemm_mfma(
        const _Float16* __restrict__ A16, const _Float16* __restrict__ W16,
        const float* __restrict__ me, const int* __restrict__ masks,
        _Float16* __restrict__ xgf, _Float16* __restrict__ xgb) {
    __shared__ _Float16 As[4096];
    __shared__ _Float16 Bs[4096];
    const int bid = blockIdx.x;
    const int logical = (bid & 7) * 192 + (bid >> 3);
    const int mt = logical / 12, nt = logical % 12;
    const int bm = mt * 128, bn = nt * 128;
    const int tid = threadIdx.x;
    const int w = tid >> 6, lane = tid & 63;
    const int wr = w >> 1, wc = w & 1;

    const int rl = lane & 15;
    const int kb = (lane >> 4) * 16;
    const int st0 = w, st1 = 4 + w;
    const char* gA0 = (const char*)A16 + (size_t)(bm + st0 * 16 + rl) * 2048 + kb;
    const char* gA1 = (const char*)A16 + (size_t)(bm + st1 * 16 + rl) * 2048 + kb;
    const char* gB0 = (const char*)W16 + (size_t)(bn + st0 * 16 + rl) * 2048 + kb;
    const char* gB1 = (const char*)W16 + (size_t)(bn + st1 * 16 + rl) * 2048 + kb;
    char* lA0 = (char*)As + w * 1024;
    char* lA1 = (char*)As + 4096 + w * 1024;
    char* lB0 = (char*)Bs + w * 1024;
    char* lB1 = (char*)Bs + 4096 + w * 1024;

    f32x4 acc[4][4];
    #pragma unroll
    for (int m = 0; m < 4; ++m)
        #pragma unroll
        for (int n = 0; n < 4; ++n)
            acc[m][n] = (f32x4){0.f, 0.f, 0.f, 0.f};

    for (int kB = 0; kB < 2048; kB += 64) {
        gload16(gA0 + kB, lA0);
        gload16(gA1 + kB, lA1);
        gload16(gB0 + kB, lB0);
        gload16(gB1 + kB, lB1);
        __syncthreads();
        f16x8 af[4], bf[4];
        #pragma unroll
        for (int m = 0; m < 4; ++m)
            af[m] = *reinterpret_cast<const f16x8*>(
                (const char*)As + (wr * 4 + m) * 1024 + lane * 16);
        #pragma unroll
        for (int n = 0; n < 4; ++n)
            bf[n] = *reinterpret_cast<const f16x8*>(
                (const char*)Bs + (wc * 4 + n) * 1024 + lane * 16);
        #pragma unroll
        for (int m = 0; m < 4; ++m)
            #pragma unroll
            for (int n = 0; n < 4; ++n)
                acc[m][n] = __builtin_amdgcn_mfma_f32_16x16x32_f16(
                    af[m], bf[n], acc[m][n], 0, 0, 0);
        __syncthreads();
    }

    const int qr = (lane >> 4) * 4;
    const int cc = lane & 15;
    #pragma unroll
    for (int m = 0; m < 4; ++m) {
        #pragma unroll
        for (int q = 0; q < 4; ++q) {
            const int bt = bm + wr * 64 + m * 16 + qr + q;
            const int mk = masks[bt];
            const int b = bt >> 7, t = bt & 127;
            #pragma unroll
            for (int n = 0; n < 4; ++n) {
                const int col = bn + wc * 64 + n * 16 + cc;
                const int dir = col >= G3_;
                const int g = col - dir * G3_;
                float v = acc[m][n][q] + me[dir * (2 * G3_) + mk * G3_ + g];
                _Float16* dst = (dir ? xgb : xgf) + ((size_t)(t * B_ + b)) * G3_ + g;
                *dst = (_Float16)v;
            }
        }
    }
}

// ---------------- GRU scan (round-12 body: int8 VMEM stream, f16 xg) ---------
__device__ __forceinline__ int sdot4(uint_t a, uint_t b, int c) {
#if __has_builtin(__builtin_amdgcn_sdot4)
    return __builtin_amdgcn_sdot4((int)a, (int)b, c, false);
#else
    int r = c;
    r += ((int)(a << 24) >> 24) * ((int)(b << 24) >> 24);
    r += ((int)(a << 16) >> 24) * ((int)(b << 16) >> 24);
    r += ((int)(a << 8) >> 24) * ((int)(b << 8) >> 24);
    r += ((int)a >> 24) * ((int)b >> 24);
    return r;
#endif
}

// One block = one (batch row, direction). 512 threads: j = tid&255, kh = tid>>8.
// int8 weights streamed from L2 each step (24 uint4/thread) — proven floor
// ~0.97 us/step (L2/L1 BW bound; register residency is allocator-blocked per
// rounds 8-13, LDS partition regressed per round 14). xg read as f16 (halved
// HBM fetch vs round 12).
__global__ __launch_bounds__(512, 1) void k_gru(
        const _Float16* __restrict__ xgf, const _Float16* __restrict__ xgb,
        const uint_t* __restrict__ wi8, const float* __restrict__ dq,
        const float* __restrict__ bhhf, const float* __restrict__ bhhb,
        const int* __restrict__ lens, _Float16* __restrict__ ctx16p) {
    const int dir = blockIdx.y;
    const int b = blockIdx.x;
    const int tid = threadIdx.x;
    const int j = tid & 255;
    const int kh = tid >> 8;
    const _Float16* xg = dir ? xgb : xgf;
    const float* bhh = dir ? bhhb : bhhf;
    const uint4* wp4 = (const uint4*)wi8 + (size_t)dir * (2 * 8 * 3 * 256);
    _Float16* c16 = ctx16p + (size_t)b * (T_ + 2) * D_;

    __shared__ uint_t hq_s[64];          // 256 i8 h values
    __shared__ int part[3][256];

    // zero the pad rows
    c16[tid] = (_Float16)0.f;
    c16[(size_t)(T_ + 1) * D_ + tid] = (_Float16)0.f;

    // load this thread's weights: 3 gates x 8 16-wide chunks (24 uint4)
    uint4 w4[3][8];
    #pragma unroll
    for (int q = 0; q < 8; ++q)
        #pragma unroll
        for (int p = 0; p < 3; ++p)
            w4[p][q] = wp4[((size_t)((kh * 8 + q) * 3 + p)) * 256 + j];

    if (tid < 64) hq_s[tid] = 0u;
    const int len = lens[b];
    const float dq0 = dq[dir * G3_ + j];
    const float dq1 = dq[dir * G3_ + 256 + j];
    const float dq2 = dq[dir * G3_ + 512 + j];
    const float bh0 = bhh[j], bh1 = bhh[H_ + j], bh2 = bhh[2 * H_ + j];
    float hcur = 0.f;
    float g0 = 0.f, g1 = 0.f, g2 = 0.f;
    int t = dir ? (T_ - 1) : 0;
    if (kh == 0) {
        const _Float16* r = xg + ((size_t)(t * B_ + b)) * G3_;
        g0 = (float)r[j]; g1 = (float)r[H_ + j]; g2 = (float)r[2 * H_ + j];
    }
    __syncthreads();

    for (int s = 0; s < T_; ++s) {
        const int tn = dir ? (T_ - 2 - s) : (s + 1);
        float n0 = 0.f, n1 = 0.f, n2 = 0.f;
        if (kh == 0 && s < T_ - 1) {
            const _Float16* r = xg + ((size_t)(tn * B_ + b)) * G3_;
            n0 = (float)r[j]; n1 = (float)r[H_ + j]; n2 = (float)r[2 * H_ + j];
        }
        int a0 = 0, a1 = 0, a2 = 0;
        const uint4* hv = (const uint4*)hq_s + kh * 8;
        #pragma unroll
        for (int q = 0; q < 8; ++q) {
            uint4 h4 = hv[q];
            a0 = sdot4(w4[0][q].x, h4.x, a0); a0 = sdot4(w4[0][q].y, h4.y, a0);
            a0 = sdot4(w4[0][q].z, h4.z, a0); a0 = sdot4(w4[0][q].w, h4.w, a0);
            a1 = sdot4(w4[1][q].x, h4.x, a1); a1 = sdot4(w4[1][q].y, h4.y, a1);
            a1 = sdot4(w4[1][q].z, h4.z, a1); a1 = sdot4(w4[1][q].w, h4.w, a1);
            a2 = sdot4(w4[2][q].x, h4.x, a2); a2 = sdot4(w4[2][q].y, h4.y, a2);
            a2 = sdot4(w4[2][q].z, h4.z, a2); a2 = sdot4(w4[2][q].w, h4.w, a2);
        }
        if (kh == 1) {
            part[0][j] = a0; part[1][j] = a1; part[2][j] = a2;
        }
        __syncthreads();
        if (kh == 0) {
            float A0 = (float)(a0 + part[0][j]) * dq0;
            float A1 = (float)(a1 + part[1][j]) * dq1;
            float A2 = (float)(a2 + part[2][j]) * dq2;
            float rg = 1.f / (1.f + expf(-(g0 + A0 + bh0)));
            float zg = 1.f / (1.f + expf(-(g1 + A1 + bh1)));
            float ng = tanhf(g2 + rg * (A2 + bh2));
            float v = (1.f - zg) * ng + zg * hcur;
            hcur = (t < len) ? v : hcur;
            c16[(size_t)(t + 1) * D_ + dir * H_ + j] = (_Float16)hcur;
            int qi = __float2int_rn(hcur * 127.f);
            ((signed char*)hq_s)[j] = (signed char)qi;
        }
        __syncthreads();
        g0 = n0; g1 = n1; g2 = n2;
        t = tn;
    }
}

// ---------------- conv1d as MFMA GEMM ----------------
__global__ __launch_bounds__(256) void k_conv_mfma(
        const _Float16* __restrict__ C16, const _Float16* __restrict__ W2,
        const float* __restrict__ cb, float* __restrict__ ctx2) {
    __shared__ _Float16 As[4096];
    __shared__ _Float16 Bs[4096];
    const int b = blockIdx.x >> 1;
    const int nt = blockIdx.x & 1;
    const int bn = nt * 128;
    const int tid = threadIdx.x;
    const int w = tid >> 6, lane = tid & 63;
    const int wr = w >> 1, wc = w & 1;
    const int rl = lane & 15;
    const int kb = (lane >> 4) * 16;
    const char* gA0 = (const char*)C16 + ((size_t)(b * (T_ + 2) + w * 16 + rl)) * 1024 + kb;
    const char* gA1 = (const char*)C16 + ((size_t)(b * (T_ + 2) + 64 + w * 16 + rl)) * 1024 + kb;
    const char* gB0 = (const char*)W2 + (size_t)(bn + w * 16 + rl) * 3072 + kb;
    const char* gB1 = (const char*)W2 + (size_t)(bn + 64 + w * 16 + rl) * 3072 + kb;
    char* lA0 = (char*)As + w * 1024;
    char* lA1 = (char*)As + 4096 + w * 1024;
    char* lB0 = (char*)Bs + w * 1024;
    char* lB1 = (char*)Bs + 4096 + w * 1024;

    f32x4 acc[4][4];
    #pragma unroll
    for (int m = 0; m < 4; ++m)
        #pragma unroll
        for (int n = 0; n < 4; ++n)
            acc[m][n] = (f32x4){0.f, 0.f, 0.f, 0.f};

    for (int kB = 0; kB < 3072; kB += 64) {
        gload16(gA0 + kB, lA0);
        gload16(gA1 + kB, lA1);
        gload16(gB0 + kB, lB0);
        gload16(gB1 + kB, lB1);
        __syncthreads();
        f16x8 af[4], bf[4];
        #pragma unroll
        for (int m = 0; m < 4; ++m)
            af[m] = *reinterpret_cast<const f16x8*>(
                (const char*)As + (wr * 4 + m) * 1024 + lane * 16);
        #pragma unroll
        for (int n = 0; n < 4; ++n)
            bf[n] = *reinterpret_cast<const f16x8*>(
                (const char*)Bs + (wc * 4 + n) * 1024 + lane * 16);
        #pragma unroll
        for (int m = 0; m < 4; ++m)
            #pragma unroll
            for (int n = 0; n < 4; ++n)
                acc[m][n] = __builtin_amdgcn_mfma_f32_16x16x32_f16(
                    af[m], bf[n], acc[m][n], 0, 0, 0);
        __syncthreads();
    }

    const int qr = (lane >> 4) * 4;
    const int cc = lane & 15;
    #pragma unroll
    for (int m = 0; m < 4; ++m) {
        #pragma unroll
        for (int q = 0; q < 4; ++q) {
            const int t = wr * 64 + m * 16 + qr + q;
            #pragma unroll
            for (int n = 0; n < 4; ++n) {
                const int co = bn + wc * 64 + n * 16 + cc;
                float v = acc[m][n][q] + cb[co];
                ctx2[((size_t)(b * T_ + t)) * CO_ + co] = fmaxf(v, 0.f);
            }
        }
    }
}

// ---------------- feats + CRF + pooled head (wave-parallel) ----------------
__global__ __launch_bounds__(256) void k_head(
        const float* __restrict__ ctx2, const float* __restrict__ W_tri,
        const float* __restrict__ b_tri, const float* __restrict__ trans,
        const float* __restrict__ W_lab, const float* __restrict__ b_lab,
        const int* __restrict__ lens, const int* __restrict__ labels,
        float* __restrict__ loss_b, float* __restrict__ spsum_b) {
    const int b = blockIdx.x;
    const int tid = threadIdx.x;
    const int w = tid >> 6, lane = tid & 63;
    __shared__ float f_s[T_][4];
    __shared__ float al[T_][4];
    __shared__ float be[T_][4];
    __shared__ float sp_s[T_];
    __shared__ float sv_s[CO_];
    __shared__ float sred[4];
    __shared__ float s_spsum;
    const int len = lens[b];
    const float* base = ctx2 + (size_t)b * T_ * CO_;

    {
        float wt[4][4];
        #pragma unroll
        for (int k = 0; k < 4; ++k)
            #pragma unroll
            for (int q = 0; q < 4; ++q)
                wt[k][q] = W_tri[k * CO_ + lane + 64 * q];
        float bt0 = b_tri[0], bt1 = b_tri[1], bt2 = b_tri[2], bt3 = b_tri[3];
        for (int t = w; t < T_; t += 4) {
            const float* row = base + (size_t)t * CO_;
            float v0 = row[lane], v1 = row[lane + 64],
                  v2 = row[lane + 128], v3 = row[lane + 192];
            float p0 = v0 * wt[0][0] + v1 * wt[0][1] + v2 * wt[0][2] + v3 * wt[0][3];
            float p1 = v0 * wt[1][0] + v1 * wt[1][1] + v2 * wt[1][2] + v3 * wt[1][3];
            float p2 = v0 * wt[2][0] + v1 * wt[2][1] + v2 * wt[2][2] + v3 * wt[2][3];
            float p3 = v0 * wt[3][0] + v1 * wt[3][1] + v2 * wt[3][2] + v3 * wt[3][3];
            #pragma unroll
            for (int off = 32; off > 0; off >>= 1) {
                p0 += __shfl_xor(p0, off);
                p1 += __shfl_xor(p1, off);
                p2 += __shfl_xor(p2, off);
                p3 += __shfl_xor(p3, off);
            }
            if (lane == 0) {
                f_s[t][0] = p0 + bt0; f_s[t][1] = p1 + bt1;
                f_s[t][2] = p2 + bt2; f_s[t][3] = p3 + bt3;
            }
        }
    }
    __syncthreads();

    if (w == 0 && lane < 4) {
        const int j = lane;
        float tc0 = trans[0 * 4 + j], tc1 = trans[1 * 4 + j],
              tc2 = trans[2 * 4 + j], tc3 = trans[3 * 4 + j];
        float a = f_s[0][j];
        al[0][j] = a;
        for (int t = 1; t < T_; ++t) {
            float a0 = __shfl(a, 0), a1 = __shfl(a, 1),
                  a2 = __shfl(a, 2), a3 = __shfl(a, 3);
            float s0 = a0 + tc0, s1 = a1 + tc1, s2 = a2 + tc2, s3 = a3 + tc3;
            float m = fmaxf(fmaxf(s0, s1), fmaxf(s2, s3));
            float sum = expf(s0 - m) + expf(s1 - m) + expf(s2 - m) + expf(s3 - m);
            float an = f_s[t][j] + m + logf(sum);
            if (t < len) a = an;
            al[t][j] = a;
        }
    } else if (w == 1 && lane < 4) {
        const int i = lane;
        float tr0 = trans[i * 4 + 0], tr1 = trans[i * 4 + 1],
              tr2 = trans[i * 4 + 2], tr3 = trans[i * 4 + 3];
        float bb = 0.f;
        be[T_ - 1][i] = 0.f;
        for (int t = T_ - 2; t >= 0; --t) {
            float b0 = __shfl(bb, 0), b1 = __shfl(bb, 1),
                  b2 = __shfl(bb, 2), b3 = __shfl(bb, 3);
            float s0 = tr0 + f_s[t + 1][0] + b0;
            float s1 = tr1 + f_s[t + 1][1] + b1;
            float s2 = tr2 + f_s[t + 1][2] + b2;
            float s3 = tr3 + f_s[t + 1][3] + b3;
            float m = fmaxf(fmaxf(s0, s1), fmaxf(s2, s3));
            float sum = expf(s0 - m) + expf(s1 - m) + expf(s2 - m) + expf(s3 - m);
            float bn = m + logf(sum);
            if (t + 1 < len) bb = bn;
            be[t][i] = bb;
        }
    }
    __syncthreads();

    if (tid < T_) {
        int t = tid;
        float s0 = al[t][0] + be[t][0];
        float s1 = al[t][1] + be[t][1];
        float s2 = al[t][2] + be[t][2];
        float s3 = al[t][3] + be[t][3];
        float m = fmaxf(fmaxf(s0, s1), fmaxf(s2, s3));
        float e0 = expf(s0 - m), e1 = expf(s1 - m), e2 = expf(s2 - m), e3 = expf(s3 - m);
        float p1 = e1 / (e0 + e1 + e2 + e3);
        sp_s[t] = (t < len) ? p1 : 0.f;
    }
    __syncthreads();
    if (w == 0) {
        float s = sp_s[lane] + sp_s[lane + 64];
        #pragma unroll
        for (int off = 32; off > 0; off >>= 1) s += __shfl_xor(s, off);
        if (lane == 0) s_spsum = s;
    }
    __syncthreads();
    const float spsum = s_spsum;

    {
        float acc0 = 0.f, acc1 = 0.f, acc2 = 0.f, acc3 = 0.f;
        #pragma unroll 2
        for (int t = 0; t < T_; t += 4) {
            acc0 += sp_s[t + 0] * base[(size_t)(t + 0) * CO_ + tid];
            acc1 += sp_s[t + 1] * base[(size_t)(t + 1) * CO_ + tid];
            acc2 += sp_s[t + 2] * base[(size_t)(t + 2) * CO_ + tid];
            acc3 += sp_s[t + 3] * base[(size_t)(t + 3) * CO_ + tid];
        }
        sv_s[tid] = (acc0 + acc1 + acc2 + acc3) * 2.f / spsum;
    }
    __syncthreads();

    if (w < 3) {
        const float* wl_ = W_lab + w * CO_;
        float p = sv_s[lane] * wl_[lane] + sv_s[lane + 64] * wl_[lane + 64]
                + sv_s[lane + 128] * wl_[lane + 128] + sv_s[lane + 192] * wl_[lane + 192];
        #pragma unroll
        for (int off = 32; off > 0; off >>= 1) p += __shfl_xor(p, off);
        if (lane == 0) sred[w] = p + b_lab[w];
    }
    __syncthreads();
    if (tid == 0) {
        float m = fmaxf(sred[0], fmaxf(sred[1], sred[2]));
        float lse = m + logf(expf(sred[0] - m) + expf(sred[1] - m) + expf(sred[2] - m));
        loss_b[b] = lse - sred[labels[b]];
        spsum_b[b] = spsum;
    }
}

__global__ void k_final(const float* __restrict__ loss_b, const float* __restrict__ spsum_b,
                        const float* __restrict__ trans, float* __restrict__ out) {
    __shared__ float s1[128], s2[128];
    int tid = threadIdx.x;
    s1[tid] = loss_b[tid];
    s2[tid] = spsum_b[tid];
    __syncthreads();
    for (int off = 64; off > 0; off >>= 1) {
        if (tid < off) { s1[tid] += s1[tid + off]; s2[tid] += s2[tid + off]; }
        __syncthreads();
    }
    if (tid == 0) {
        float pena = fmaxf(trans[1 * 4 + 0] - trans[0 * 4 + 0], 0.f)
                   + fmaxf(trans[0 * 4 + 1] - trans[1 * 4 + 1], 0.f);
        out[0] = s1[0] / (float)B_;
        out[1] = 0.1f * pena + 0.1f * (s2[0] / (float)B_);
    }
}

// ---------------- launch ----------------
extern "C" void kernel_launch(void* const* d_in, const int* in_sizes, int n_in,
                              void* d_out, int out_size, void* d_ws, size_t ws_size,
                              hipStream_t stream) {
    const float* sents   = (const float*)d_in[0];
    const int*   masks   = (const int*)d_in[1];
    const int*   labels  = (const int*)d_in[2];
    const int*   lens    = (const int*)d_in[3];
    const float* mask_emb= (const float*)d_in[4];
    const float* Wih_f   = (const float*)d_in[5];
    const float* Whh_f   = (const float*)d_in[6];
    const float* bih_f   = (const float*)d_in[7];
    const float* bhh_f   = (const float*)d_in[8];
    const float* Wih_b   = (const float*)d_in[9];
    const float* Whh_b   = (const float*)d_in[10];
    const float* bih_b   = (const float*)d_in[11];
    const float* bhh_b   = (const float*)d_in[12];
    const float* conv_w  = (const float*)d_in[13];
    const float* conv_b  = (const float*)d_in[14];
    const float* W_tri   = (const float*)d_in[15];
    const float* b_tri   = (const float*)d_in[16];
    const float* trans   = (const float*)d_in[17];
    const float* W_lab   = (const float*)d_in[18];
    const float* b_lab   = (const float*)d_in[19];
    float* out = (float*)d_out;
    float* ws = (float*)d_ws;

    const size_t o_xgf  = 0;
    const size_t o_xgb  = o_xgf  + (size_t)B_ * T_ * G3_;
    const size_t o_ctx  = o_xgb  + (size_t)B_ * T_ * G3_;   // sents16, then ctx16p
    const size_t o_ctx2 = o_ctx  + (size_t)B_ * T_ * D_;    // W16, then ctx2 f32
    const size_t o_wp   = o_ctx2 + (size_t)B_ * T_ * CO_;   // wi8 + dq + inv
    const size_t o_me   = o_wp   + (size_t)2 * 32 * 3 * 256 * 4;
    const size_t o_w2   = o_me   + 2 * 2 * G3_;
    const size_t o_lossb= o_w2   + (size_t)D_ * 3 * CO_;
    const size_t o_spsum= o_lossb + B_;

    _Float16* xgf16 = (_Float16*)(ws + o_xgf);
    _Float16* xgb16 = (_Float16*)(ws + o_xgb);
    float* ctx  = ws + o_ctx;
    float* ctx2 = ws + o_ctx2;
    uint_t* wi8 = (uint_t*)(ws + o_wp);                 // 98304 uints
    float* dq   = ws + o_wp + 98304;                    // 1536
    float* invs = ws + o_wp + 98304 + 1536;             // 1536
    float* me   = ws + o_me;
    unsigned short* W2 = (unsigned short*)(ws + o_w2);
    float* lossb = ws + o_lossb;
    float* spsumb = ws + o_spsum;

    _Float16* sents16 = (_Float16*)ctx;
    _Float16* ctx16p = (_Float16*)ctx;
    _Float16* W16 = (_Float16*)ctx2;    // consumed by gemm before ctx2 written

    k_prep_me<<<12, 256, 0, stream>>>(mask_emb, Wih_f, bih_f, Wih_b, bih_b, me);
    k_scale<<<6, 256, 0, stream>>>(Whh_f, Whh_b, dq, invs);
    k_quant<<<384, 256, 0, stream>>>(Whh_f, Whh_b, invs, wi8);
    k_prep_w2<<<1536, 256, 0, stream>>>(conv_w, W2);
    k_cvt_sents<<<8192, 256, 0, stream>>>(sents, (uint_t*)sents16);
    k_cvt_w<<<768, 256, 0, stream>>>(Wih_f, Wih_b, (uint_t*)W16);
    k_gemm_mfma<<<1536, 256, 0, stream>>>(sents16, W16, me, masks, xgf16, xgb16);
    k_gru<<<dim3(B_, 2), 512, 0, stream>>>(xgf16, xgb16, wi8, dq, bhh_f, bhh_b, lens, ctx16p);
    k_conv_mfma<<<256, 256, 0, stream>>>(ctx16p, (const _Float16*)W2, conv_b, ctx2);
    k_head<<<128, 256, 0, stream>>>(ctx2, W_tri, b_tri, trans, W_lab, b_lab,
                                    lens, labels, lossb, spsumb);
    k_final<<<1, 128, 0, stream>>>(lossb, spsumb, trans, out);
}

// Round 16
// 369.784 us; speedup vs baseline: 1.1379x; 1.0828x over previous
//
#include <hip/hip_runtime.h>
#include <hip/hip_bf16.h>
#include <math.h>

#define B_ 128
#define T_ 128
#define E_ 1024
#define IN_ 1074
#define H_ 256
#define G3_ 768
#define D_ 512
#define CO_ 256

typedef unsigned int uint_t;
typedef _Float16 v2h __attribute__((ext_vector_type(2)));
typedef _Float16 f16x8 __attribute__((ext_vector_type(8)));
typedef float f32x4 __attribute__((ext_vector_type(4)));

__device__ __forceinline__ uint_t pk2(float a, float b) {
    uint_t u0 = (uint_t)__builtin_bit_cast(unsigned short, (_Float16)a);
    uint_t u1 = (uint_t)__builtin_bit_cast(unsigned short, (_Float16)b);
    return u0 | (u1 << 16);
}

// ---------------- fused prep mega-kernel ----------------
// block ranges:
//   [0,8192)        cvt_sents   (f32 -> packed f16)
//   [8192,8960)     cvt_w       (Wih f32 -> f16 GEMM layout)
//   [8960,10496)    prep_w2     (conv_w -> f16 GEMM layout)
//   [10496,12032)   scale+quant (Whh row max -> dq + int8 pack, fused)
//   [12032,12044)   prep_me     (mask-emb partial projections + bih)
__global__ __launch_bounds__(256) void k_prep_all(
        const float* __restrict__ sents, uint_t* __restrict__ s16,
        const float* __restrict__ Wih_f, const float* __restrict__ Wih_b,
        uint_t* __restrict__ W16,
        const float* __restrict__ conv_w, unsigned short* __restrict__ W2,
        const float* __restrict__ Whh_f, const float* __restrict__ Whh_b,
        float* __restrict__ dq, uint_t* __restrict__ wi8,
        const float* __restrict__ mask_emb,
        const float* __restrict__ bih_f, const float* __restrict__ bih_b,
        float* __restrict__ me) {
    __shared__ float red[4];
    __shared__ signed char sb[256];
    const int blk = blockIdx.x;
    const int tid = threadIdx.x;

    if (blk < 8192) {
        // ---- cvt_sents ----
        int i = blk * 256 + tid;
        float4 a = reinterpret_cast<const float4*>(sents)[i * 2];
        float4 b = reinterpret_cast<const float4*>(sents)[i * 2 + 1];
        uint4 o;
        o.x = pk2(a.x, a.y); o.y = pk2(a.z, a.w);
        o.z = pk2(b.x, b.y); o.w = pk2(b.z, b.w);
        reinterpret_cast<uint4*>(s16)[i] = o;
    } else if (blk < 8960) {
        // ---- cvt_w: W16[n][k] = f16(Wih_dir[g][k]) ----
        int i = (blk - 8192) * 256 + tid;    // 0..196607
        int n = i >> 7, kq = i & 127;
        int dir = n >= G3_;
        int g = n - dir * G3_;
        const float* src = (dir ? Wih_b : Wih_f) + (size_t)g * IN_ + kq * 8;
        float2 a = reinterpret_cast<const float2*>(src)[0];
        float2 b = reinterpret_cast<const float2*>(src)[1];
        float2 c = reinterpret_cast<const float2*>(src)[2];
        float2 d = reinterpret_cast<const float2*>(src)[3];
        uint4 o;
        o.x = pk2(a.x, a.y); o.y = pk2(b.x, b.y);
        o.z = pk2(c.x, c.y); o.w = pk2(d.x, d.y);
        reinterpret_cast<uint4*>(W16)[i] = o;
    } else if (blk < 10496) {
        // ---- prep_w2: W2[co][j*512+d] = f16(conv_w[co][d][j]) ----
        int i = (blk - 8960) * 256 + tid;    // 0..393215
        int co = i / 1536;
        int k = i % 1536;
        int j = k >> 9;
        int d = k & 511;
        float v = conv_w[(size_t)co * (D_ * 3) + d * 3 + j];
        W2[i] = __builtin_bit_cast(unsigned short, (_Float16)v);
    } else if (blk < 12032) {
        // ---- fused scale+quant: one block per Whh row ----
        int r = blk - 10496;                 // 0..1535
        int d = r / G3_;
        int g = r % G3_;
        const float* W = (d ? Whh_b : Whh_f) + (size_t)g * H_;
        float v = W[tid];
        float m = fabsf(v);
        #pragma unroll
        for (int off = 32; off > 0; off >>= 1) m = fmaxf(m, __shfl_xor(m, off));
        if ((tid & 63) == 0) red[tid >> 6] = m;
        __syncthreads();
        float mm = fmaxf(fmaxf(red[0], red[1]), fmaxf(red[2], red[3]));
        float iv = (mm > 0.f) ? 127.f / mm : 0.f;
        if (tid == 0) dq[r] = mm / 16129.f;
        int q = __float2int_rn(v * iv);
        q = max(-127, min(127, q));
        sb[tid] = (signed char)q;
        __syncthreads();
        if (tid < 64) {
            int k0 = tid * 4;
            int kh = k0 >> 7;
            int k0h = k0 & 127;
            int q16 = k0h >> 4;
            int w = (k0h >> 2) & 3;
            int p = g >> 8;
            int j = g & 255;
            uint_t u = (uint_t)(unsigned char)sb[k0]
                     | ((uint_t)(unsigned char)sb[k0 + 1] << 8)
                     | ((uint_t)(unsigned char)sb[k0 + 2] << 16)
                     | ((uint_t)(unsigned char)sb[k0 + 3] << 24);
            size_t idx = ((((size_t)(d * 2 + kh) * 8 + q16) * 3 + p) * 256 + j) * 4 + w;
            wi8[idx] = u;
        }
    } else {
        // ---- prep_me ----
        int idx = (blk - 12032) * 256 + tid; // 0..3071
        if (idx >= 2 * 2 * G3_) return;
        int dir = idx / (2 * G3_);
        int rem = idx % (2 * G3_);
        int m = rem / G3_;
        int g = rem % G3_;
        const float* W = dir ? Wih_b : Wih_f;
        const float* bi = dir ? bih_b : bih_f;
        float acc = bi[g];
        const float* wrow = W + (size_t)g * IN_ + E_;
        const float* e = mask_emb + m * 50;
        #pragma unroll 10
        for (int c = 0; c < 50; ++c) acc += e[c] * wrow[c];
        me[idx] = acc;
    }
}

// ---------------- MFMA xg GEMM (f16 output) ----------------

__device__ __forceinline__ void gload16(const void* g, void* l) {
    __builtin_amdgcn_global_load_lds(
        (const __attribute__((address_space(1))) void*)g,
        (__attribute__((address_space(3))) void*)l, 16, 0, 0);
}

__global__ __launch_bounds__(256) void k_gemm_mfma(
        const _Float16* __restrict__ A16, const _Float16* __restrict__ W16,
        const float* __restrict__ me, const int* __restrict__ masks,
        _Float16* __restrict__ xgf, _Float16* __restrict__ xgb) {
    __shared__ _Float16 As[4096];
    __shared__ _Float16 Bs[4096];
    const int bid = blockIdx.x;
    const int logical = (bid & 7) * 192 + (bid >> 3);
    const int mt = logical / 12, nt = logical % 12;
    const int bm = mt * 128, bn = nt * 128;
    const int tid = threadIdx.x;
    const int w = tid >> 6, lane = tid & 63;
    const int wr = w >> 1, wc = w & 1;

    const int rl = lane & 15;
    const int kb = (lane >> 4) * 16;
    const int st0 = w, st1 = 4 + w;
    const char* gA0 = (const char*)A16 + (size_t)(bm + st0 * 16 + rl) * 2048 + kb;
    const char* gA1 = (const char*)A16 + (size_t)(bm + st1 * 16 + rl) * 2048 + kb;
    const char* gB0 = (const char*)W16 + (size_t)(bn + st0 * 16 + rl) * 2048 + kb;
    const char* gB1 = (const char*)W16 + (size_t)(bn + st1 * 16 + rl) * 2048 + kb;
    char* lA0 = (char*)As + w * 1024;
    char* lA1 = (char*)As + 4096 + w * 1024;
    char* lB0 = (char*)Bs + w * 1024;
    char* lB1 = (char*)Bs + 4096 + w * 1024;

    f32x4 acc[4][4];
    #pragma unroll
    for (int m = 0; m < 4; ++m)
        #pragma unroll
        for (int n = 0; n < 4; ++n)
            acc[m][n] = (f32x4){0.f, 0.f, 0.f, 0.f};

    for (int kB = 0; kB < 2048; kB += 64) {
        gload16(gA0 + kB, lA0);
        gload16(gA1 + kB, lA1);
        gload16(gB0 + kB, lB0);
        gload16(gB1 + kB, lB1);
        __syncthreads();
        f16x8 af[4], bf[4];
        #pragma unroll
        for (int m = 0; m < 4; ++m)
            af[m] = *reinterpret_cast<const f16x8*>(
                (const char*)As + (wr * 4 + m) * 1024 + lane * 16);
        #pragma unroll
        for (int n = 0; n < 4; ++n)
            bf[n] = *reinterpret_cast<const f16x8*>(
                (const char*)Bs + (wc * 4 + n) * 1024 + lane * 16);
        #pragma unroll
        for (int m = 0; m < 4; ++m)
            #pragma unroll
            for (int n = 0; n < 4; ++n)
                acc[m][n] = __builtin_amdgcn_mfma_f32_16x16x32_f16(
                    af[m], bf[n], acc[m][n], 0, 0, 0);
        __syncthreads();
    }

    const int qr = (lane >> 4) * 4;
    const int cc = lane & 15;
    #pragma unroll
    for (int m = 0; m < 4; ++m) {
        #pragma unroll
        for (int q = 0; q < 4; ++q) {
            const int bt = bm + wr * 64 + m * 16 + qr + q;
            const int mk = masks[bt];
            const int b = bt >> 7, t = bt & 127;
            #pragma unroll
            for (int n = 0; n < 4; ++n) {
                const int col = bn + wc * 64 + n * 16 + cc;
                const int dir = col >= G3_;
                const int g = col - dir * G3_;
                float v = acc[m][n][q] + me[dir * (2 * G3_) + mk * G3_ + g];
                _Float16* dst = (dir ? xgb : xgf) + ((size_t)(t * B_ + b)) * G3_ + g;
                *dst = (_Float16)v;
            }
        }
    }
}

// ---------------- GRU scan (int8 VMEM stream, f16 xg) ----------------
__device__ __forceinline__ int sdot4(uint_t a, uint_t b, int c) {
#if __has_builtin(__builtin_amdgcn_sdot4)
    return __builtin_amdgcn_sdot4((int)a, (int)b, c, false);
#else
    int r = c;
    r += ((int)(a << 24) >> 24) * ((int)(b << 24) >> 24);
    r += ((int)(a << 16) >> 24) * ((int)(b << 16) >> 24);
    r += ((int)(a << 8) >> 24) * ((int)(b << 8) >> 24);
    r += ((int)a >> 24) * ((int)b >> 24);
    return r;
#endif
}

__global__ __launch_bounds__(512, 1) void k_gru(
        const _Float16* __restrict__ xgf, const _Float16* __restrict__ xgb,
        const uint_t* __restrict__ wi8, const float* __restrict__ dq,
        const float* __restrict__ bhhf, const float* __restrict__ bhhb,
        const int* __restrict__ lens, _Float16* __restrict__ ctx16p) {
    const int dir = blockIdx.y;
    const int b = blockIdx.x;
    const int tid = threadIdx.x;
    const int j = tid & 255;
    const int kh = tid >> 8;
    const _Float16* xg = dir ? xgb : xgf;
    const float* bhh = dir ? bhhb : bhhf;
    const uint4* wp4 = (const uint4*)wi8 + (size_t)dir * (2 * 8 * 3 * 256);
    _Float16* c16 = ctx16p + (size_t)b * (T_ + 2) * D_;

    __shared__ uint_t hq_s[64];          // 256 i8 h values
    __shared__ int part[3][256];

    c16[tid] = (_Float16)0.f;
    c16[(size_t)(T_ + 1) * D_ + tid] = (_Float16)0.f;

    uint4 w4[3][8];
    #pragma unroll
    for (int q = 0; q < 8; ++q)
        #pragma unroll
        for (int p = 0; p < 3; ++p)
            w4[p][q] = wp4[((size_t)((kh * 8 + q) * 3 + p)) * 256 + j];

    if (tid < 64) hq_s[tid] = 0u;
    const int len = lens[b];
    const float dq0 = dq[dir * G3_ + j];
    const float dq1 = dq[dir * G3_ + 256 + j];
    const float dq2 = dq[dir * G3_ + 512 + j];
    const float bh0 = bhh[j], bh1 = bhh[H_ + j], bh2 = bhh[2 * H_ + j];
    float hcur = 0.f;
    float g0 = 0.f, g1 = 0.f, g2 = 0.f;
    int t = dir ? (T_ - 1) : 0;
    if (kh == 0) {
        const _Float16* r = xg + ((size_t)(t * B_ + b)) * G3_;
        g0 = (float)r[j]; g1 = (float)r[H_ + j]; g2 = (float)r[2 * H_ + j];
    }
    __syncthreads();

    for (int s = 0; s < T_; ++s) {
        const int tn = dir ? (T_ - 2 - s) : (s + 1);
        float n0 = 0.f, n1 = 0.f, n2 = 0.f;
        if (kh == 0 && s < T_ - 1) {
            const _Float16* r = xg + ((size_t)(tn * B_ + b)) * G3_;
            n0 = (float)r[j]; n1 = (float)r[H_ + j]; n2 = (float)r[2 * H_ + j];
        }
        int a0 = 0, a1 = 0, a2 = 0;
        const uint4* hv = (const uint4*)hq_s + kh * 8;
        #pragma unroll
        for (int q = 0; q < 8; ++q) {
            uint4 h4 = hv[q];
            a0 = sdot4(w4[0][q].x, h4.x, a0); a0 = sdot4(w4[0][q].y, h4.y, a0);
            a0 = sdot4(w4[0][q].z, h4.z, a0); a0 = sdot4(w4[0][q].w, h4.w, a0);
            a1 = sdot4(w4[1][q].x, h4.x, a1); a1 = sdot4(w4[1][q].y, h4.y, a1);
            a1 = sdot4(w4[1][q].z, h4.z, a1); a1 = sdot4(w4[1][q].w, h4.w, a1);
            a2 = sdot4(w4[2][q].x, h4.x, a2); a2 = sdot4(w4[2][q].y, h4.y, a2);
            a2 = sdot4(w4[2][q].z, h4.z, a2); a2 = sdot4(w4[2][q].w, h4.w, a2);
        }
        if (kh == 1) {
            part[0][j] = a0; part[1][j] = a1; part[2][j] = a2;
        }
        __syncthreads();
        if (kh == 0) {
            float A0 = (float)(a0 + part[0][j]) * dq0;
            float A1 = (float)(a1 + part[1][j]) * dq1;
            float A2 = (float)(a2 + part[2][j]) * dq2;
            float rg = 1.f / (1.f + expf(-(g0 + A0 + bh0)));
            float zg = 1.f / (1.f + expf(-(g1 + A1 + bh1)));
            float ng = tanhf(g2 + rg * (A2 + bh2));
            float v = (1.f - zg) * ng + zg * hcur;
            hcur = (t < len) ? v : hcur;
            c16[(size_t)(t + 1) * D_ + dir * H_ + j] = (_Float16)hcur;
            int qi = __float2int_rn(hcur * 127.f);
            ((signed char*)hq_s)[j] = (signed char)qi;
        }
        __syncthreads();
        g0 = n0; g1 = n1; g2 = n2;
        t = tn;
    }
}

// ---------------- conv1d as MFMA GEMM ----------------
__global__ __launch_bounds__(256) void k_conv_mfma(
        const _Float16* __restrict__ C16, const _Float16* __restrict__ W2,
        const float* __restrict__ cb, float* __restrict__ ctx2) {
    __shared__ _Float16 As[4096];
    __shared__ _Float16 Bs[4096];
    const int b = blockIdx.x >> 1;
    const int nt = blockIdx.x & 1;
    const int bn = nt * 128;
    const int tid = threadIdx.x;
    const int w = tid >> 6, lane = tid & 63;
    const int wr = w >> 1, wc = w & 1;
    const int rl = lane & 15;
    const int kb = (lane >> 4) * 16;
    const char* gA0 = (const char*)C16 + ((size_t)(b * (T_ + 2) + w * 16 + rl)) * 1024 + kb;
    const char* gA1 = (const char*)C16 + ((size_t)(b * (T_ + 2) + 64 + w * 16 + rl)) * 1024 + kb;
    const char* gB0 = (const char*)W2 + (size_t)(bn + w * 16 + rl) * 3072 + kb;
    const char* gB1 = (const char*)W2 + (size_t)(bn + 64 + w * 16 + rl) * 3072 + kb;
    char* lA0 = (char*)As + w * 1024;
    char* lA1 = (char*)As + 4096 + w * 1024;
    char* lB0 = (char*)Bs + w * 1024;
    char* lB1 = (char*)Bs + 4096 + w * 1024;

    f32x4 acc[4][4];
    #pragma unroll
    for (int m = 0; m < 4; ++m)
        #pragma unroll
        for (int n = 0; n < 4; ++n)
            acc[m][n] = (f32x4){0.f, 0.f, 0.f, 0.f};

    for (int kB = 0; kB < 3072; kB += 64) {
        gload16(gA0 + kB, lA0);
        gload16(gA1 + kB, lA1);
        gload16(gB0 + kB, lB0);
        gload16(gB1 + kB, lB1);
        __syncthreads();
        f16x8 af[4], bf[4];
        #pragma unroll
        for (int m = 0; m < 4; ++m)
            af[m] = *reinterpret_cast<const f16x8*>(
                (const char*)As + (wr * 4 + m) * 1024 + lane * 16);
        #pragma unroll
        for (int n = 0; n < 4; ++n)
            bf[n] = *reinterpret_cast<const f16x8*>(
                (const char*)Bs + (wc * 4 + n) * 1024 + lane * 16);
        #pragma unroll
        for (int m = 0; m < 4; ++m)
            #pragma unroll
            for (int n = 0; n < 4; ++n)
                acc[m][n] = __builtin_amdgcn_mfma_f32_16x16x32_f16(
                    af[m], bf[n], acc[m][n], 0, 0, 0);
        __syncthreads();
    }

    const int qr = (lane >> 4) * 4;
    const int cc = lane & 15;
    #pragma unroll
    for (int m = 0; m < 4; ++m) {
        #pragma unroll
        for (int q = 0; q < 4; ++q) {
            const int t = wr * 64 + m * 16 + qr + q;
            #pragma unroll
            for (int n = 0; n < 4; ++n) {
                const int co = bn + wc * 64 + n * 16 + cc;
                float v = acc[m][n][q] + cb[co];
                ctx2[((size_t)(b * T_ + t)) * CO_ + co] = fmaxf(v, 0.f);
            }
        }
    }
}

// ---------------- feats + CRF + pooled head (wave-parallel) ----------------
__global__ __launch_bounds__(256) void k_head(
        const float* __restrict__ ctx2, const float* __restrict__ W_tri,
        const float* __restrict__ b_tri, const float* __restrict__ trans,
        const float* __restrict__ W_lab, const float* __restrict__ b_lab,
        const int* __restrict__ lens, const int* __restrict__ labels,
        float* __restrict__ loss_b, float* __restrict__ spsum_b) {
    const int b = blockIdx.x;
    const int tid = threadIdx.x;
    const int w = tid >> 6, lane = tid & 63;
    __shared__ float f_s[T_][4];
    __shared__ float al[T_][4];
    __shared__ float be[T_][4];
    __shared__ float sp_s[T_];
    __shared__ float sv_s[CO_];
    __shared__ float sred[4];
    __shared__ float s_spsum;
    const int len = lens[b];
    const float* base = ctx2 + (size_t)b * T_ * CO_;

    {
        float wt[4][4];
        #pragma unroll
        for (int k = 0; k < 4; ++k)
            #pragma unroll
            for (int q = 0; q < 4; ++q)
                wt[k][q] = W_tri[k * CO_ + lane + 64 * q];
        float bt0 = b_tri[0], bt1 = b_tri[1], bt2 = b_tri[2], bt3 = b_tri[3];
        for (int t = w; t < T_; t += 4) {
            const float* row = base + (size_t)t * CO_;
            float v0 = row[lane], v1 = row[lane + 64],
                  v2 = row[lane + 128], v3 = row[lane + 192];
            float p0 = v0 * wt[0][0] + v1 * wt[0][1] + v2 * wt[0][2] + v3 * wt[0][3];
            float p1 = v0 * wt[1][0] + v1 * wt[1][1] + v2 * wt[1][2] + v3 * wt[1][3];
            float p2 = v0 * wt[2][0] + v1 * wt[2][1] + v2 * wt[2][2] + v3 * wt[2][3];
            float p3 = v0 * wt[3][0] + v1 * wt[3][1] + v2 * wt[3][2] + v3 * wt[3][3];
            #pragma unroll
            for (int off = 32; off > 0; off >>= 1) {
                p0 += __shfl_xor(p0, off);
                p1 += __shfl_xor(p1, off);
                p2 += __shfl_xor(p2, off);
                p3 += __shfl_xor(p3, off);
            }
            if (lane == 0) {
                f_s[t][0] = p0 + bt0; f_s[t][1] = p1 + bt1;
                f_s[t][2] = p2 + bt2; f_s[t][3] = p3 + bt3;
            }
        }
    }
    __syncthreads();

    if (w == 0 && lane < 4) {
        const int j = lane;
        float tc0 = trans[0 * 4 + j], tc1 = trans[1 * 4 + j],
              tc2 = trans[2 * 4 + j], tc3 = trans[3 * 4 + j];
        float a = f_s[0][j];
        al[0][j] = a;
        for (int t = 1; t < T_; ++t) {
            float a0 = __shfl(a, 0), a1 = __shfl(a, 1),
                  a2 = __shfl(a, 2), a3 = __shfl(a, 3);
            float s0 = a0 + tc0, s1 = a1 + tc1, s2 = a2 + tc2, s3 = a3 + tc3;
            float m = fmaxf(fmaxf(s0, s1), fmaxf(s2, s3));
            float sum = expf(s0 - m) + expf(s1 - m) + expf(s2 - m) + expf(s3 - m);
            float an = f_s[t][j] + m + logf(sum);
            if (t < len) a = an;
            al[t][j] = a;
        }
    } else if (w == 1 && lane < 4) {
        const int i = lane;
        float tr0 = trans[i * 4 + 0], tr1 = trans[i * 4 + 1],
              tr2 = trans[i * 4 + 2], tr3 = trans[i * 4 + 3];
        float bb = 0.f;
        be[T_ - 1][i] = 0.f;
        for (int t = T_ - 2; t >= 0; --t) {
            float b0 = __shfl(bb, 0), b1 = __shfl(bb, 1),
                  b2 = __shfl(bb, 2), b3 = __shfl(bb, 3);
            float s0 = tr0 + f_s[t + 1][0] + b0;
            float s1 = tr1 + f_s[t + 1][1] + b1;
            float s2 = tr2 + f_s[t + 1][2] + b2;
            float s3 = tr3 + f_s[t + 1][3] + b3;
            float m = fmaxf(fmaxf(s0, s1), fmaxf(s2, s3));
            float sum = expf(s0 - m) + expf(s1 - m) + expf(s2 - m) + expf(s3 - m);
            float bn = m + logf(sum);
            if (t + 1 < len) bb = bn;
            be[t][i] = bb;
        }
    }
    __syncthreads();

    if (tid < T_) {
        int t = tid;
        float s0 = al[t][0] + be[t][0];
        float s1 = al[t][1] + be[t][1];
        float s2 = al[t][2] + be[t][2];
        float s3 = al[t][3] + be[t][3];
        float m = fmaxf(fmaxf(s0, s1), fmaxf(s2, s3));
        float e0 = expf(s0 - m), e1 = expf(s1 - m), e2 = expf(s2 - m), e3 = expf(s3 - m);
        float p1 = e1 / (e0 + e1 + e2 + e3);
        sp_s[t] = (t < len) ? p1 : 0.f;
    }
    __syncthreads();
    if (w == 0) {
        float s = sp_s[lane] + sp_s[lane + 64];
        #pragma unroll
        for (int off = 32; off > 0; off >>= 1) s += __shfl_xor(s, off);
        if (lane == 0) s_spsum = s;
    }
    __syncthreads();
    const float spsum = s_spsum;

    {
        float acc0 = 0.f, acc1 = 0.f, acc2 = 0.f, acc3 = 0.f;
        #pragma unroll 2
        for (int t = 0; t < T_; t += 4) {
            acc0 += sp_s[t + 0] * base[(size_t)(t + 0) * CO_ + tid];
            acc1 += sp_s[t + 1] * base[(size_t)(t + 1) * CO_ + tid];
            acc2 += sp_s[t + 2] * base[(size_t)(t + 2) * CO_ + tid];
            acc3 += sp_s[t + 3] * base[(size_t)(t + 3) * CO_ + tid];
        }
        sv_s[tid] = (acc0 + acc1 + acc2 + acc3) * 2.f / spsum;
    }
    __syncthreads();

    if (w < 3) {
        const float* wl_ = W_lab + w * CO_;
        float p = sv_s[lane] * wl_[lane] + sv_s[lane + 64] * wl_[lane + 64]
                + sv_s[lane + 128] * wl_[lane + 128] + sv_s[lane + 192] * wl_[lane + 192];
        #pragma unroll
        for (int off = 32; off > 0; off >>= 1) p += __shfl_xor(p, off);
        if (lane == 0) sred[w] = p + b_lab[w];
    }
    __syncthreads();
    if (tid == 0) {
        float m = fmaxf(sred[0], fmaxf(sred[1], sred[2]));
        float lse = m + logf(expf(sred[0] - m) + expf(sred[1] - m) + expf(sred[2] - m));
        loss_b[b] = lse - sred[labels[b]];
        spsum_b[b] = spsum;
    }
}

__global__ void k_final(const float* __restrict__ loss_b, const float* __restrict__ spsum_b,
                        const float* __restrict__ trans, float* __restrict__ out) {
    __shared__ float s1[128], s2[128];
    int tid = threadIdx.x;
    s1[tid] = loss_b[tid];
    s2[tid] = spsum_b[tid];
    __syncthreads();
    for (int off = 64; off > 0; off >>= 1) {
        if (tid < off) { s1[tid] += s1[tid + off]; s2[tid] += s2[tid + off]; }
        __syncthreads();
    }
    if (tid == 0) {
        float pena = fmaxf(trans[1 * 4 + 0] - trans[0 * 4 + 0], 0.f)
                   + fmaxf(trans[0 * 4 + 1] - trans[1 * 4 + 1], 0.f);
        out[0] = s1[0] / (float)B_;
        out[1] = 0.1f * pena + 0.1f * (s2[0] / (float)B_);
    }
}

// ---------------- launch ----------------
extern "C" void kernel_launch(void* const* d_in, const int* in_sizes, int n_in,
                              void* d_out, int out_size, void* d_ws, size_t ws_size,
                              hipStream_t stream) {
    const float* sents   = (const float*)d_in[0];
    const int*   masks   = (const int*)d_in[1];
    const int*   labels  = (const int*)d_in[2];
    const int*   lens    = (const int*)d_in[3];
    const float* mask_emb= (const float*)d_in[4];
    const float* Wih_f   = (const float*)d_in[5];
    const float* Whh_f   = (const float*)d_in[6];
    const float* bih_f   = (const float*)d_in[7];
    const float* bhh_f   = (const float*)d_in[8];
    const float* Wih_b   = (const float*)d_in[9];
    const float* Whh_b   = (const float*)d_in[10];
    const float* bih_b   = (const float*)d_in[11];
    const float* bhh_b   = (const float*)d_in[12];
    const float* conv_w  = (const float*)d_in[13];
    const float* conv_b  = (const float*)d_in[14];
    const float* W_tri   = (const float*)d_in[15];
    const float* b_tri   = (const float*)d_in[16];
    const float* trans   = (const float*)d_in[17];
    const float* W_lab   = (const float*)d_in[18];
    const float* b_lab   = (const float*)d_in[19];
    float* out = (float*)d_out;
    float* ws = (float*)d_ws;

    const size_t o_xgf  = 0;
    const size_t o_xgb  = o_xgf  + (size_t)B_ * T_ * G3_;
    const size_t o_ctx  = o_xgb  + (size_t)B_ * T_ * G3_;   // sents16, then ctx16p
    const size_t o_ctx2 = o_ctx  + (size_t)B_ * T_ * D_;    // W16, then ctx2 f32
    const size_t o_wp   = o_ctx2 + (size_t)B_ * T_ * CO_;   // wi8 + dq
    const size_t o_me   = o_wp   + (size_t)2 * 32 * 3 * 256 * 4;
    const size_t o_w2   = o_me   + 2 * 2 * G3_;
    const size_t o_lossb= o_w2   + (size_t)D_ * 3 * CO_;
    const size_t o_spsum= o_lossb + B_;

    _Float16* xgf16 = (_Float16*)(ws + o_xgf);
    _Float16* xgb16 = (_Float16*)(ws + o_xgb);
    float* ctx  = ws + o_ctx;
    float* ctx2 = ws + o_ctx2;
    uint_t* wi8 = (uint_t*)(ws + o_wp);                 // 98304 uints
    float* dq   = ws + o_wp + 98304;                    // 1536
    float* me   = ws + o_me;
    unsigned short* W2 = (unsigned short*)(ws + o_w2);
    float* lossb = ws + o_lossb;
    float* spsumb = ws + o_spsum;

    _Float16* sents16 = (_Float16*)ctx;
    _Float16* ctx16p = (_Float16*)ctx;
    _Float16* W16 = (_Float16*)ctx2;    // consumed by gemm before ctx2 written

    k_prep_all<<<12044, 256, 0, stream>>>(
        sents, (uint_t*)sents16, Wih_f, Wih_b, (uint_t*)W16,
        conv_w, W2, Whh_f, Whh_b, dq, wi8, mask_emb, bih_f, bih_b, me);
    k_gemm_mfma<<<1536, 256, 0, stream>>>(sents16, W16, me, masks, xgf16, xgb16);
    k_gru<<<dim3(B_, 2), 512, 0, stream>>>(xgf16, xgb16, wi8, dq, bhh_f, bhh_b, lens, ctx16p);
    k_conv_mfma<<<256, 256, 0, stream>>>(ctx16p, (const _Float16*)W2, conv_b, ctx2);
    k_head<<<128, 256, 0, stream>>>(ctx2, W_tri, b_tri, trans, W_lab, b_lab,
                                    lens, labels, lossb, spsumb);
    k_final<<<1, 128, 0, stream>>>(lossb, spsumb, trans, out);
}

// Round 17
// 369.781 us; speedup vs baseline: 1.1379x; 1.0000x over previous
//
#include <hip/hip_runtime.h>
#include <hip/hip_bf16.h>
#include <math.h>

#define B_ 128
#define T_ 128
#define E_ 1024
#define IN_ 1074
#define H_ 256
#define G3_ 768
#define D_ 512
#define CO_ 256

typedef unsigned int uint_t;
typedef _Float16 v2h __attribute__((ext_vector_type(2)));
typedef _Float16 f16x8 __attribute__((ext_vector_type(8)));
typedef float f32x4 __attribute__((ext_vector_type(4)));

__device__ __forceinline__ uint_t pk2(float a, float b) {
    uint_t u0 = (uint_t)__builtin_bit_cast(unsigned short, (_Float16)a);
    uint_t u1 = (uint_t)__builtin_bit_cast(unsigned short, (_Float16)b);
    return u0 | (u1 << 16);
}

// ---------------- fused prep mega-kernel ----------------
__global__ __launch_bounds__(256) void k_prep_all(
        const float* __restrict__ sents, uint_t* __restrict__ s16,
        const float* __restrict__ Wih_f, const float* __restrict__ Wih_b,
        uint_t* __restrict__ W16,
        const float* __restrict__ conv_w, unsigned short* __restrict__ W2,
        const float* __restrict__ Whh_f, const float* __restrict__ Whh_b,
        float* __restrict__ dq, uint_t* __restrict__ wi8,
        const float* __restrict__ mask_emb,
        const float* __restrict__ bih_f, const float* __restrict__ bih_b,
        float* __restrict__ me) {
    __shared__ float red[4];
    __shared__ signed char sb[256];
    const int blk = blockIdx.x;
    const int tid = threadIdx.x;

    if (blk < 8192) {
        int i = blk * 256 + tid;
        float4 a = reinterpret_cast<const float4*>(sents)[i * 2];
        float4 b = reinterpret_cast<const float4*>(sents)[i * 2 + 1];
        uint4 o;
        o.x = pk2(a.x, a.y); o.y = pk2(a.z, a.w);
        o.z = pk2(b.x, b.y); o.w = pk2(b.z, b.w);
        reinterpret_cast<uint4*>(s16)[i] = o;
    } else if (blk < 8960) {
        int i = (blk - 8192) * 256 + tid;    // 0..196607
        int n = i >> 7, kq = i & 127;
        int dir = n >= G3_;
        int g = n - dir * G3_;
        const float* src = (dir ? Wih_b : Wih_f) + (size_t)g * IN_ + kq * 8;
        float2 a = reinterpret_cast<const float2*>(src)[0];
        float2 b = reinterpret_cast<const float2*>(src)[1];
        float2 c = reinterpret_cast<const float2*>(src)[2];
        float2 d = reinterpret_cast<const float2*>(src)[3];
        uint4 o;
        o.x = pk2(a.x, a.y); o.y = pk2(b.x, b.y);
        o.z = pk2(c.x, c.y); o.w = pk2(d.x, d.y);
        reinterpret_cast<uint4*>(W16)[i] = o;
    } else if (blk < 10496) {
        int i = (blk - 8960) * 256 + tid;    // 0..393215
        int co = i / 1536;
        int k = i % 1536;
        int j = k >> 9;
        int d = k & 511;
        float v = conv_w[(size_t)co * (D_ * 3) + d * 3 + j];
        W2[i] = __builtin_bit_cast(unsigned short, (_Float16)v);
    } else if (blk < 12032) {
        int r = blk - 10496;                 // 0..1535
        int d = r / G3_;
        int g = r % G3_;
        const float* W = (d ? Whh_b : Whh_f) + (size_t)g * H_;
        float v = W[tid];
        float m = fabsf(v);
        #pragma unroll
        for (int off = 32; off > 0; off >>= 1) m = fmaxf(m, __shfl_xor(m, off));
        if ((tid & 63) == 0) red[tid >> 6] = m;
        __syncthreads();
        float mm = fmaxf(fmaxf(red[0], red[1]), fmaxf(red[2], red[3]));
        float iv = (mm > 0.f) ? 127.f / mm : 0.f;
        if (tid == 0) dq[r] = mm / 16129.f;
        int q = __float2int_rn(v * iv);
        q = max(-127, min(127, q));
        sb[tid] = (signed char)q;
        __syncthreads();
        if (tid < 64) {
            int k0 = tid * 4;
            int kh = k0 >> 7;
            int k0h = k0 & 127;
            int q16 = k0h >> 4;
            int w = (k0h >> 2) & 3;
            int p = g >> 8;
            int j = g & 255;
            uint_t u = (uint_t)(unsigned char)sb[k0]
                     | ((uint_t)(unsigned char)sb[k0 + 1] << 8)
                     | ((uint_t)(unsigned char)sb[k0 + 2] << 16)
                     | ((uint_t)(unsigned char)sb[k0 + 3] << 24);
            size_t idx = ((((size_t)(d * 2 + kh) * 8 + q16) * 3 + p) * 256 + j) * 4 + w;
            wi8[idx] = u;
        }
    } else {
        int idx = (blk - 12032) * 256 + tid; // 0..3071
        if (idx >= 2 * 2 * G3_) return;
        int dir = idx / (2 * G3_);
        int rem = idx % (2 * G3_);
        int m = rem / G3_;
        int g = rem % G3_;
        const float* W = dir ? Wih_b : Wih_f;
        const float* bi = dir ? bih_b : bih_f;
        float acc = bi[g];
        const float* wrow = W + (size_t)g * IN_ + E_;
        const float* e = mask_emb + m * 50;
        #pragma unroll 10
        for (int c = 0; c < 50; ++c) acc += e[c] * wrow[c];
        me[idx] = acc;
    }
}

// ---------------- MFMA xg GEMM (f16 output) ----------------

__device__ __forceinline__ void gload16(const void* g, void* l) {
    __builtin_amdgcn_global_load_lds(
        (const __attribute__((address_space(1))) void*)g,
        (__attribute__((address_space(3))) void*)l, 16, 0, 0);
}

__global__ __launch_bounds__(256) void k_gemm_mfma(
        const _Float16* __restrict__ A16, const _Float16* __restrict__ W16,
        const float* __restrict__ me, const int* __restrict__ masks,
        _Float16* __restrict__ xgf, _Float16* __restrict__ xgb) {
    __shared__ _Float16 As[4096];
    __shared__ _Float16 Bs[4096];
    const int bid = blockIdx.x;
    const int logical = (bid & 7) * 192 + (bid >> 3);
    const int mt = logical / 12, nt = logical % 12;
    const int bm = mt * 128, bn = nt * 128;
    const int tid = threadIdx.x;
    const int w = tid >> 6, lane = tid & 63;
    const int wr = w >> 1, wc = w & 1;

    const int rl = lane & 15;
    const int kb = (lane >> 4) * 16;
    const int st0 = w, st1 = 4 + w;
    const char* gA0 = (const char*)A16 + (size_t)(bm + st0 * 16 + rl) * 2048 + kb;
    const char* gA1 = (const char*)A16 + (size_t)(bm + st1 * 16 + rl) * 2048 + kb;
    const char* gB0 = (const char*)W16 + (size_t)(bn + st0 * 16 + rl) * 2048 + kb;
    const char* gB1 = (const char*)W16 + (size_t)(bn + st1 * 16 + rl) * 2048 + kb;
    char* lA0 = (char*)As + w * 1024;
    char* lA1 = (char*)As + 4096 + w * 1024;
    char* lB0 = (char*)Bs + w * 1024;
    char* lB1 = (char*)Bs + 4096 + w * 1024;

    f32x4 acc[4][4];
    #pragma unroll
    for (int m = 0; m < 4; ++m)
        #pragma unroll
        for (int n = 0; n < 4; ++n)
            acc[m][n] = (f32x4){0.f, 0.f, 0.f, 0.f};

    for (int kB = 0; kB < 2048; kB += 64) {
        gload16(gA0 + kB, lA0);
        gload16(gA1 + kB, lA1);
        gload16(gB0 + kB, lB0);
        gload16(gB1 + kB, lB1);
        __syncthreads();
        f16x8 af[4], bf[4];
        #pragma unroll
        for (int m = 0; m < 4; ++m)
            af[m] = *reinterpret_cast<const f16x8*>(
                (const char*)As + (wr * 4 + m) * 1024 + lane * 16);
        #pragma unroll
        for (int n = 0; n < 4; ++n)
            bf[n] = *reinterpret_cast<const f16x8*>(
                (const char*)Bs + (wc * 4 + n) * 1024 + lane * 16);
        #pragma unroll
        for (int m = 0; m < 4; ++m)
            #pragma unroll
            for (int n = 0; n < 4; ++n)
                acc[m][n] = __builtin_amdgcn_mfma_f32_16x16x32_f16(
                    af[m], bf[n], acc[m][n], 0, 0, 0);
        __syncthreads();
    }

    const int qr = (lane >> 4) * 4;
    const int cc = lane & 15;
    #pragma unroll
    for (int m = 0; m < 4; ++m) {
        #pragma unroll
        for (int q = 0; q < 4; ++q) {
            const int bt = bm + wr * 64 + m * 16 + qr + q;
            const int mk = masks[bt];
            const int b = bt >> 7, t = bt & 127;
            #pragma unroll
            for (int n = 0; n < 4; ++n) {
                const int col = bn + wc * 64 + n * 16 + cc;
                const int dir = col >= G3_;
                const int g = col - dir * G3_;
                float v = acc[m][n][q] + me[dir * (2 * G3_) + mk * G3_ + g];
                _Float16* dst = (dir ? xgb : xgf) + ((size_t)(t * B_ + b)) * G3_ + g;
                *dst = (_Float16)v;
            }
        }
    }
}

// ---------------- GRU scan (int8 VMEM stream, f16 xg) ----------------
__device__ __forceinline__ int sdot4(uint_t a, uint_t b, int c) {
#if __has_builtin(__builtin_amdgcn_sdot4)
    return __builtin_amdgcn_sdot4((int)a, (int)b, c, false);
#else
    int r = c;
    r += ((int)(a << 24) >> 24) * ((int)(b << 24) >> 24);
    r += ((int)(a << 16) >> 24) * ((int)(b << 16) >> 24);
    r += ((int)(a << 8) >> 24) * ((int)(b << 8) >> 24);
    r += ((int)a >> 24) * ((int)b >> 24);
    return r;
#endif
}

__global__ __launch_bounds__(512, 1) void k_gru(
        const _Float16* __restrict__ xgf, const _Float16* __restrict__ xgb,
        const uint_t* __restrict__ wi8, const float* __restrict__ dq,
        const float* __restrict__ bhhf, const float* __restrict__ bhhb,
        const int* __restrict__ lens, _Float16* __restrict__ ctx16p) {
    const int dir = blockIdx.y;
    const int b = blockIdx.x;
    const int tid = threadIdx.x;
    const int j = tid & 255;
    const int kh = tid >> 8;
    const _Float16* xg = dir ? xgb : xgf;
    const float* bhh = dir ? bhhb : bhhf;
    const uint4* wp4 = (const uint4*)wi8 + (size_t)dir * (2 * 8 * 3 * 256);
    _Float16* c16 = ctx16p + (size_t)b * (T_ + 2) * D_;

    __shared__ uint_t hq_s[64];          // 256 i8 h values
    __shared__ int part[3][256];

    c16[tid] = (_Float16)0.f;
    c16[(size_t)(T_ + 1) * D_ + tid] = (_Float16)0.f;

    uint4 w4[3][8];
    #pragma unroll
    for (int q = 0; q < 8; ++q)
        #pragma unroll
        for (int p = 0; p < 3; ++p)
            w4[p][q] = wp4[((size_t)((kh * 8 + q) * 3 + p)) * 256 + j];

    if (tid < 64) hq_s[tid] = 0u;
    const int len = lens[b];
    const float dq0 = dq[dir * G3_ + j];
    const float dq1 = dq[dir * G3_ + 256 + j];
    const float dq2 = dq[dir * G3_ + 512 + j];
    const float bh0 = bhh[j], bh1 = bhh[H_ + j], bh2 = bhh[2 * H_ + j];
    float hcur = 0.f;
    float g0 = 0.f, g1 = 0.f, g2 = 0.f;
    int t = dir ? (T_ - 1) : 0;
    if (kh == 0) {
        const _Float16* r = xg + ((size_t)(t * B_ + b)) * G3_;
        g0 = (float)r[j]; g1 = (float)r[H_ + j]; g2 = (float)r[2 * H_ + j];
    }
    __syncthreads();

    for (int s = 0; s < T_; ++s) {
        const int tn = dir ? (T_ - 2 - s) : (s + 1);
        float n0 = 0.f, n1 = 0.f, n2 = 0.f;
        if (kh == 0 && s < T_ - 1) {
            const _Float16* r = xg + ((size_t)(tn * B_ + b)) * G3_;
            n0 = (float)r[j]; n1 = (float)r[H_ + j]; n2 = (float)r[2 * H_ + j];
        }
        int a0 = 0, a1 = 0, a2 = 0;
        const uint4* hv = (const uint4*)hq_s + kh * 8;
        #pragma unroll
        for (int q = 0; q < 8; ++q) {
            uint4 h4 = hv[q];
            a0 = sdot4(w4[0][q].x, h4.x, a0); a0 = sdot4(w4[0][q].y, h4.y, a0);
            a0 = sdot4(w4[0][q].z, h4.z, a0); a0 = sdot4(w4[0][q].w, h4.w, a0);
            a1 = sdot4(w4[1][q].x, h4.x, a1); a1 = sdot4(w4[1][q].y, h4.y, a1);
            a1 = sdot4(w4[1][q].z, h4.z, a1); a1 = sdot4(w4[1][q].w, h4.w, a1);
            a2 = sdot4(w4[2][q].x, h4.x, a2); a2 = sdot4(w4[2][q].y, h4.y, a2);
            a2 = sdot4(w4[2][q].z, h4.z, a2); a2 = sdot4(w4[2][q].w, h4.w, a2);
        }
        if (kh == 1) {
            part[0][j] = a0; part[1][j] = a1; part[2][j] = a2;
        }
        __syncthreads();
        if (kh == 0) {
            float A0 = (float)(a0 + part[0][j]) * dq0;
            float A1 = (float)(a1 + part[1][j]) * dq1;
            float A2 = (float)(a2 + part[2][j]) * dq2;
            float rg = 1.f / (1.f + expf(-(g0 + A0 + bh0)));
            float zg = 1.f / (1.f + expf(-(g1 + A1 + bh1)));
            float ng = tanhf(g2 + rg * (A2 + bh2));
            float v = (1.f - zg) * ng + zg * hcur;
            hcur = (t < len) ? v : hcur;
            c16[(size_t)(t + 1) * D_ + dir * H_ + j] = (_Float16)hcur;
            int qi = __float2int_rn(hcur * 127.f);
            ((signed char*)hq_s)[j] = (signed char)qi;
        }
        __syncthreads();
        g0 = n0; g1 = n1; g2 = n2;
        t = tn;
    }
}

// ---------------- conv1d as MFMA GEMM (f16 output) ----------------
__global__ __launch_bounds__(256) void k_conv_mfma(
        const _Float16* __restrict__ C16, const _Float16* __restrict__ W2,
        const float* __restrict__ cb, _Float16* __restrict__ ctx2) {
    __shared__ _Float16 As[4096];
    __shared__ _Float16 Bs[4096];
    const int b = blockIdx.x >> 1;
    const int nt = blockIdx.x & 1;
    const int bn = nt * 128;
    const int tid = threadIdx.x;
    const int w = tid >> 6, lane = tid & 63;
    const int wr = w >> 1, wc = w & 1;
    const int rl = lane & 15;
    const int kb = (lane >> 4) * 16;
    const char* gA0 = (const char*)C16 + ((size_t)(b * (T_ + 2) + w * 16 + rl)) * 1024 + kb;
    const char* gA1 = (const char*)C16 + ((size_t)(b * (T_ + 2) + 64 + w * 16 + rl)) * 1024 + kb;
    const char* gB0 = (const char*)W2 + (size_t)(bn + w * 16 + rl) * 3072 + kb;
    const char* gB1 = (const char*)W2 + (size_t)(bn + 64 + w * 16 + rl) * 3072 + kb;
    char* lA0 = (char*)As + w * 1024;
    char* lA1 = (char*)As + 4096 + w * 1024;
    char* lB0 = (char*)Bs + w * 1024;
    char* lB1 = (char*)Bs + 4096 + w * 1024;

    f32x4 acc[4][4];
    #pragma unroll
    for (int m = 0; m < 4; ++m)
        #pragma unroll
        for (int n = 0; n < 4; ++n)
            acc[m][n] = (f32x4){0.f, 0.f, 0.f, 0.f};

    for (int kB = 0; kB < 3072; kB += 64) {
        gload16(gA0 + kB, lA0);
        gload16(gA1 + kB, lA1);
        gload16(gB0 + kB, lB0);
        gload16(gB1 + kB, lB1);
        __syncthreads();
        f16x8 af[4], bf[4];
        #pragma unroll
        for (int m = 0; m < 4; ++m)
            af[m] = *reinterpret_cast<const f16x8*>(
                (const char*)As + (wr * 4 + m) * 1024 + lane * 16);
        #pragma unroll
        for (int n = 0; n < 4; ++n)
            bf[n] = *reinterpret_cast<const f16x8*>(
                (const char*)Bs + (wc * 4 + n) * 1024 + lane * 16);
        #pragma unroll
        for (int m = 0; m < 4; ++m)
            #pragma unroll
            for (int n = 0; n < 4; ++n)
                acc[m][n] = __builtin_amdgcn_mfma_f32_16x16x32_f16(
                    af[m], bf[n], acc[m][n], 0, 0, 0);
        __syncthreads();
    }

    const int qr = (lane >> 4) * 4;
    const int cc = lane & 15;
    #pragma unroll
    for (int m = 0; m < 4; ++m) {
        #pragma unroll
        for (int q = 0; q < 4; ++q) {
            const int t = wr * 64 + m * 16 + qr + q;
            #pragma unroll
            for (int n = 0; n < 4; ++n) {
                const int co = bn + wc * 64 + n * 16 + cc;
                float v = acc[m][n][q] + cb[co];
                ctx2[((size_t)(b * T_ + t)) * CO_ + co] = (_Float16)fmaxf(v, 0.f);
            }
        }
    }
}

// ---------------- feats + CRF + pooled head (f16 ctx2) ----------------
__global__ __launch_bounds__(256) void k_head(
        const _Float16* __restrict__ ctx2, const float* __restrict__ W_tri,
        const float* __restrict__ b_tri, const float* __restrict__ trans,
        const float* __restrict__ W_lab, const float* __restrict__ b_lab,
        const int* __restrict__ lens, const int* __restrict__ labels,
        float* __restrict__ loss_b, float* __restrict__ spsum_b) {
    const int b = blockIdx.x;
    const int tid = threadIdx.x;
    const int w = tid >> 6, lane = tid & 63;
    __shared__ float f_s[T_][4];
    __shared__ float al[T_][4];
    __shared__ float be[T_][4];
    __shared__ float sp_s[T_];
    __shared__ float sv_s[CO_];
    __shared__ float sred[4];
    __shared__ float s_spsum;
    const int len = lens[b];
    const _Float16* base = ctx2 + (size_t)b * T_ * CO_;

    {
        float wt[4][4];
        #pragma unroll
        for (int k = 0; k < 4; ++k)
            #pragma unroll
            for (int q = 0; q < 4; ++q)
                wt[k][q] = W_tri[k * CO_ + lane + 64 * q];
        float bt0 = b_tri[0], bt1 = b_tri[1], bt2 = b_tri[2], bt3 = b_tri[3];
        for (int t = w; t < T_; t += 4) {
            const _Float16* row = base + (size_t)t * CO_;
            float v0 = (float)row[lane], v1 = (float)row[lane + 64],
                  v2 = (float)row[lane + 128], v3 = (float)row[lane + 192];
            float p0 = v0 * wt[0][0] + v1 * wt[0][1] + v2 * wt[0][2] + v3 * wt[0][3];
            float p1 = v0 * wt[1][0] + v1 * wt[1][1] + v2 * wt[1][2] + v3 * wt[1][3];
            float p2 = v0 * wt[2][0] + v1 * wt[2][1] + v2 * wt[2][2] + v3 * wt[2][3];
            float p3 = v0 * wt[3][0] + v1 * wt[3][1] + v2 * wt[3][2] + v3 * wt[3][3];
            #pragma unroll
            for (int off = 32; off > 0; off >>= 1) {
                p0 += __shfl_xor(p0, off);
                p1 += __shfl_xor(p1, off);
                p2 += __shfl_xor(p2, off);
                p3 += __shfl_xor(p3, off);
            }
            if (lane == 0) {
                f_s[t][0] = p0 + bt0; f_s[t][1] = p1 + bt1;
                f_s[t][2] = p2 + bt2; f_s[t][3] = p3 + bt3;
            }
        }
    }
    __syncthreads();

    if (w == 0 && lane < 4) {
        const int j = lane;
        float tc0 = trans[0 * 4 + j], tc1 = trans[1 * 4 + j],
              tc2 = trans[2 * 4 + j], tc3 = trans[3 * 4 + j];
        float a = f_s[0][j];
        al[0][j] = a;
        for (int t = 1; t < T_; ++t) {
            float a0 = __shfl(a, 0), a1 = __shfl(a, 1),
                  a2 = __shfl(a, 2), a3 = __shfl(a, 3);
            float s0 = a0 + tc0, s1 = a1 + tc1, s2 = a2 + tc2, s3 = a3 + tc3;
            float m = fmaxf(fmaxf(s0, s1), fmaxf(s2, s3));
            float sum = expf(s0 - m) + expf(s1 - m) + expf(s2 - m) + expf(s3 - m);
            float an = f_s[t][j] + m + logf(sum);
            if (t < len) a = an;
            al[t][j] = a;
        }
    } else if (w == 1 && lane < 4) {
        const int i = lane;
        float tr0 = trans[i * 4 + 0], tr1 = trans[i * 4 + 1],
              tr2 = trans[i * 4 + 2], tr3 = trans[i * 4 + 3];
        float bb = 0.f;
        be[T_ - 1][i] = 0.f;
        for (int t = T_ - 2; t >= 0; --t) {
            float b0 = __shfl(bb, 0), b1 = __shfl(bb, 1),
                  b2 = __shfl(bb, 2), b3 = __shfl(bb, 3);
            float s0 = tr0 + f_s[t + 1][0] + b0;
            float s1 = tr1 + f_s[t + 1][1] + b1;
            float s2 = tr2 + f_s[t + 1][2] + b2;
            float s3 = tr3 + f_s[t + 1][3] + b3;
            float m = fmaxf(fmaxf(s0, s1), fmaxf(s2, s3));
            float sum = expf(s0 - m) + expf(s1 - m) + expf(s2 - m) + expf(s3 - m);
            float bn = m + logf(sum);
            if (t + 1 < len) bb = bn;
            be[t][i] = bb;
        }
    }
    __syncthreads();

    if (tid < T_) {
        int t = tid;
        float s0 = al[t][0] + be[t][0];
        float s1 = al[t][1] + be[t][1];
        float s2 = al[t][2] + be[t][2];
        float s3 = al[t][3] + be[t][3];
        float m = fmaxf(fmaxf(s0, s1), fmaxf(s2, s3));
        float e0 = expf(s0 - m), e1 = expf(s1 - m), e2 = expf(s2 - m), e3 = expf(s3 - m);
        float p1 = e1 / (e0 + e1 + e2 + e3);
        sp_s[t] = (t < len) ? p1 : 0.f;
    }
    __syncthreads();
    if (w == 0) {
        float s = sp_s[lane] + sp_s[lane + 64];
        #pragma unroll
        for (int off = 32; off > 0; off >>= 1) s += __shfl_xor(s, off);
        if (lane == 0) s_spsum = s;
    }
    __syncthreads();
    const float spsum = s_spsum;

    {
        float acc0 = 0.f, acc1 = 0.f, acc2 = 0.f, acc3 = 0.f;
        #pragma unroll 2
        for (int t = 0; t < T_; t += 4) {
            acc0 += sp_s[t + 0] * (float)base[(size_t)(t + 0) * CO_ + tid];
            acc1 += sp_s[t + 1] * (float)base[(size_t)(t + 1) * CO_ + tid];
            acc2 += sp_s[t + 2] * (float)base[(size_t)(t + 2) * CO_ + tid];
            acc3 += sp_s[t + 3] * (float)base[(size_t)(t + 3) * CO_ + tid];
        }
        sv_s[tid] = (acc0 + acc1 + acc2 + acc3) * 2.f / spsum;
    }
    __syncthreads();

    if (w < 3) {
        const float* wl_ = W_lab + w * CO_;
        float p = sv_s[lane] * wl_[lane] + sv_s[lane + 64] * wl_[lane + 64]
                + sv_s[lane + 128] * wl_[lane + 128] + sv_s[lane + 192] * wl_[lane + 192];
        #pragma unroll
        for (int off = 32; off > 0; off >>= 1) p += __shfl_xor(p, off);
        if (lane == 0) sred[w] = p + b_lab[w];
    }
    __syncthreads();
    if (tid == 0) {
        float m = fmaxf(sred[0], fmaxf(sred[1], sred[2]));
        float lse = m + logf(expf(sred[0] - m) + expf(sred[1] - m) + expf(sred[2] - m));
        loss_b[b] = lse - sred[labels[b]];
        spsum_b[b] = spsum;
    }
}

__global__ void k_final(const float* __restrict__ loss_b, const float* __restrict__ spsum_b,
                        const float* __restrict__ trans, float* __restrict__ out) {
    __shared__ float s1[128], s2[128];
    int tid = threadIdx.x;
    s1[tid] = loss_b[tid];
    s2[tid] = spsum_b[tid];
    __syncthreads();
    for (int off = 64; off > 0; off >>= 1) {
        if (tid < off) { s1[tid] += s1[tid + off]; s2[tid] += s2[tid + off]; }
        __syncthreads();
    }
    if (tid == 0) {
        float pena = fmaxf(trans[1 * 4 + 0] - trans[0 * 4 + 0], 0.f)
                   + fmaxf(trans[0 * 4 + 1] - trans[1 * 4 + 1], 0.f);
        out[0] = s1[0] / (float)B_;
        out[1] = 0.1f * pena + 0.1f * (s2[0] / (float)B_);
    }
}

// ---------------- launch ----------------
extern "C" void kernel_launch(void* const* d_in, const int* in_sizes, int n_in,
                              void* d_out, int out_size, void* d_ws, size_t ws_size,
                              hipStream_t stream) {
    const float* sents   = (const float*)d_in[0];
    const int*   masks   = (const int*)d_in[1];
    const int*   labels  = (const int*)d_in[2];
    const int*   lens    = (const int*)d_in[3];
    const float* mask_emb= (const float*)d_in[4];
    const float* Wih_f   = (const float*)d_in[5];
    const float* Whh_f   = (const float*)d_in[6];
    const float* bih_f   = (const float*)d_in[7];
    const float* bhh_f   = (const float*)d_in[8];
    const float* Wih_b   = (const float*)d_in[9];
    const float* Whh_b   = (const float*)d_in[10];
    const float* bih_b   = (const float*)d_in[11];
    const float* bhh_b   = (const float*)d_in[12];
    const float* conv_w  = (const float*)d_in[13];
    const float* conv_b  = (const float*)d_in[14];
    const float* W_tri   = (const float*)d_in[15];
    const float* b_tri   = (const float*)d_in[16];
    const float* trans   = (const float*)d_in[17];
    const float* W_lab   = (const float*)d_in[18];
    const float* b_lab   = (const float*)d_in[19];
    float* out = (float*)d_out;
    float* ws = (float*)d_ws;

    const size_t o_xgf  = 0;
    const size_t o_xgb  = o_xgf  + (size_t)B_ * T_ * G3_;
    const size_t o_ctx  = o_xgb  + (size_t)B_ * T_ * G3_;   // sents16, then ctx16p
    const size_t o_ctx2 = o_ctx  + (size_t)B_ * T_ * D_;    // W16, then ctx2 f16
    const size_t o_wp   = o_ctx2 + (size_t)B_ * T_ * CO_;   // wi8 + dq
    const size_t o_me   = o_wp   + (size_t)2 * 32 * 3 * 256 * 4;
    const size_t o_w2   = o_me   + 2 * 2 * G3_;
    const size_t o_lossb= o_w2   + (size_t)D_ * 3 * CO_;
    const size_t o_spsum= o_lossb + B_;

    _Float16* xgf16 = (_Float16*)(ws + o_xgf);
    _Float16* xgb16 = (_Float16*)(ws + o_xgb);
    float* ctx  = ws + o_ctx;
    uint_t* wi8 = (uint_t*)(ws + o_wp);                 // 98304 uints
    float* dq   = ws + o_wp + 98304;                    // 1536
    float* me   = ws + o_me;
    unsigned short* W2 = (unsigned short*)(ws + o_w2);
    float* lossb = ws + o_lossb;
    float* spsumb = ws + o_spsum;

    _Float16* sents16 = (_Float16*)ctx;
    _Float16* ctx16p = (_Float16*)ctx;
    _Float16* W16 = (_Float16*)(ws + o_ctx2);   // consumed by gemm before ctx2 written
    _Float16* ctx2_16 = (_Float16*)(ws + o_ctx2);  // conv output (after W16 dead)

    k_prep_all<<<12044, 256, 0, stream>>>(
        sents, (uint_t*)sents16, Wih_f, Wih_b, (uint_t*)W16,
        conv_w, W2, Whh_f, Whh_b, dq, wi8, mask_emb, bih_f, bih_b, me);
    k_gemm_mfma<<<1536, 256, 0, stream>>>(sents16, W16, me, masks, xgf16, xgb16);
    k_gru<<<dim3(B_, 2), 512, 0, stream>>>(xgf16, xgb16, wi8, dq, bhh_f, bhh_b, lens, ctx16p);
    k_conv_mfma<<<256, 256, 0, stream>>>(ctx16p, (const _Float16*)W2, conv_b, ctx2_16);
    k_head<<<128, 256, 0, stream>>>(ctx2_16, W_tri, b_tri, trans, W_lab, b_lab,
                                    lens, labels, lossb, spsumb);
    k_final<<<1, 128, 0, stream>>>(lossb, spsumb, trans, out);
}